// Round 12
// baseline (483.012 us; speedup 1.0000x reference)
//
#include <hip/hip_runtime.h>

#define HWS 65536   // 256*256
#define PIT 258     // padded spatial pitch

typedef __attribute__((ext_vector_type(8))) short bf16x8;
typedef __attribute__((ext_vector_type(4))) float f32x4;
typedef unsigned int u32;
typedef unsigned short u16;

__device__ __forceinline__ u16 f2bf(float x) {
    u32 u = __float_as_uint(x);
    return (u16)((u + 0x7fffu + ((u >> 16) & 1u)) >> 16);
}
__device__ __forceinline__ float bf2f(u32 h) { return __uint_as_float(h << 16); }
__device__ __forceinline__ u32 pack2(float a, float b) {
    return (u32)f2bf(a) | ((u32)f2bf(b) << 16);
}

// ---------------- tiny helpers ----------------
__global__ void k_zero(float* __restrict__ p, int n) {
    int i = blockIdx.x * 256 + threadIdx.x;
    if (i < n) p[i] = 0.f;
}

// zero the 1-pixel border of the padded xT planes
__global__ void k_border(u16* __restrict__ xTr, u16* __restrict__ xTi) {
    int gid = blockIdx.x * 256 + threadIdx.x;
    if (gid >= 8224) return;                  // 1028 border tokens * 8 uint4
    int t = gid >> 3, j = gid & 7;
    int tok;
    if (t < 258)       tok = t;                         // top row
    else if (t < 516)  tok = 257 * PIT + (t - 258);     // bottom row
    else if (t < 772)  tok = (t - 515) * PIT;           // left col, rows 1..256
    else               tok = (t - 771) * PIT + 257;     // right col
    uint4 z = make_uint4(0, 0, 0, 0);
    *(uint4*)&xTr[(size_t)tok * 64 + j * 8] = z;
    *(uint4*)&xTi[(size_t)tok * 64 + j * 8] = z;
}

// ---------------- fold dw (3x3, per-channel complex) into qkv 1x1 weights ----------------
// WB planes [3][9][192][64] bf16: plane0 = Re(wdw*wq), plane1 = Im, plane2 = -Im
__global__ void k_fold(const float* __restrict__ qr, const float* __restrict__ qi,
                       const float* __restrict__ dr, const float* __restrict__ di,
                       u16* __restrict__ WB) {
    int i = blockIdx.x * 256 + threadIdx.x;   // over 9*192*64
    if (i >= 110592) return;
    int ci = i & 63; int rem = i >> 6; int co = rem % 192; int tap = rem / 192;
    float a = dr[co * 9 + tap], b = di[co * 9 + tap];
    float c = qr[co * 64 + ci], d = qi[co * 64 + ci];
    float re = a * c - b * d, im = a * d + b * c;
    WB[(0 * 9 + tap) * 12288 + co * 64 + ci] = f2bf(re);
    WB[(1 * 9 + tap) * 12288 + co * 64 + ci] = f2bf(im);
    WB[(2 * 9 + tap) * 12288 + co * 64 + ci] = f2bf(-im);
}

// ---------------- Kernel X: transpose+convert x -> padded xTr/xTi bf16 [PIT*PIT][64] ----------------
__global__ __launch_bounds__(256) void k_xt(const float* __restrict__ x,
                                            u16* __restrict__ xTr,
                                            u16* __restrict__ xTi) {
    __shared__ u16 Tr[64][73], Ti[64][73];
    int p0 = blockIdx.x << 6;
    int w = p0 >> 8, h0 = p0 & 255;
    int t = threadIdx.x;
    const float2* x2 = (const float2*)x;
    for (int i = t; i < 4096; i += 256) {
        int ci = i >> 6, c = i & 63;
        float2 v = x2[(size_t)ci * HWS + p0 + c];
        Tr[c][ci] = f2bf(v.x);
        Ti[c][ci] = f2bf(v.y);
    }
    __syncthreads();
    size_t dbase = ((size_t)(w + 1) * PIT + h0 + 1) * 64;
    for (int i = t; i < 4096; i += 256) {
        int rr = i >> 6, ci = i & 63;
        xTr[dbase + (size_t)rr * 64 + ci] = Tr[rr][ci];
        xTi[dbase + (size_t)rr * 64 + ci] = Ti[rr][ci];
    }
}

// ---------------- Kernel C: fused conv, 2-deep pipelined phases ----------------
// q,k -> dwp planes [4][64][HWS] u16; v -> vT [HWS][64] u32 directly.
__global__ __launch_bounds__(256) void k_conv(const u16* __restrict__ xTr,
                                              const u16* __restrict__ xTi,
                                              const u16* __restrict__ WB,
                                              u16* __restrict__ dwp,
                                              u32* __restrict__ vT) {
    __shared__ __align__(16) char smem[36992];   // A frags (36 KB) | Tep 32x257 u32 (reused)
    u32* Tep = (u32*)smem;

    const int wg = blockIdx.x;
    const int xcd = wg & 7, idx = wg >> 3;      // rows 32k..32k+31 stay on XCD k
    const int row = xcd * 32 + (idx & 31);
    const int cog = idx >> 5;                   // 0..5 -> 32 co each
    const int t = threadIdx.x, lane = t & 63, wv = t >> 6;
    const int l15 = lane & 15, l4 = lane >> 4;

    const f32x4 zz = {0.f, 0.f, 0.f, 0.f};
    f32x4 cr[2][4], ci2[2][4];
#pragma unroll
    for (int cf = 0; cf < 2; ++cf)
#pragma unroll
        for (int pf = 0; pf < 4; ++pf) { cr[cf][pf] = zz; ci2[cf][pf] = zz; }

    const int hbase = wv * 64 + l15;

    auto stageA = [&](int rt) {
        for (int i = t; i < 2304; i += 256) {
            int fid = i >> 6, ln = i & 63;
            int ks = fid & 1, cf = (fid >> 1) & 1;
            int tp = fid >> 2;                  // ct*3 + plane
            int plane = tp % 3, ct = tp / 3;
            size_t src = (size_t)plane * 110592 + (size_t)(rt * 3 + ct) * 12288
                       + (size_t)(cog * 32 + 16 * cf + (ln & 15)) * 64
                       + 32 * ks + 8 * (ln >> 4);
            *(uint4*)&smem[(ct * 12 + plane * 4 + cf * 2 + ks) * 1024 + ln * 16] =
                *(const uint4*)&WB[src];
        }
    };
    auto loadB = [&](bf16x8 (&Bb)[4][4], int rt, int ct) {
        const size_t rowbase = (size_t)(row + rt) * PIT;
#pragma unroll
        for (int pf = 0; pf < 4; ++pf) {
            size_t tk = (rowbase + hbase + pf * 16 + ct) * 64 + 8 * l4;
            Bb[pf][0] = *(const bf16x8*)&xTr[tk];
            Bb[pf][1] = *(const bf16x8*)&xTr[tk + 32];
            Bb[pf][2] = *(const bf16x8*)&xTi[tk];
            Bb[pf][3] = *(const bf16x8*)&xTi[tk + 32];
        }
    };

    bf16x8 Ba[4][4], Bc[4][4];
    loadB(Ba, 0, 0);                 // issue first-phase loads before A staging
    stageA(0);
    __syncthreads();

#pragma unroll
    for (int p = 0; p < 9; ++p) {
        const int rt = p / 3, ct = p % 3;
        bf16x8 (&Bcur)[4][4] = (p & 1) ? Bc : Ba;
        bf16x8 (&Bnxt)[4][4] = (p & 1) ? Ba : Bc;
        if (p < 8) loadB(Bnxt, (p + 1) / 3, (p + 1) % 3);   // prefetch next phase
        __builtin_amdgcn_sched_barrier(0);                   // pin issue order

        const int cb = ct * 12288;
        __builtin_amdgcn_s_setprio(1);
#pragma unroll
        for (int cf = 0; cf < 2; ++cf)
#pragma unroll
            for (int ks = 0; ks < 2; ++ks) {
                bf16x8 Ar = *(const bf16x8*)&smem[cb + (0 * 4 + cf * 2 + ks) * 1024 + lane * 16];
                bf16x8 Ai = *(const bf16x8*)&smem[cb + (1 * 4 + cf * 2 + ks) * 1024 + lane * 16];
                bf16x8 An = *(const bf16x8*)&smem[cb + (2 * 4 + cf * 2 + ks) * 1024 + lane * 16];
#pragma unroll
                for (int pf = 0; pf < 4; ++pf) {
                    cr[cf][pf]  = __builtin_amdgcn_mfma_f32_16x16x32_bf16(Ar, Bcur[pf][ks],     cr[cf][pf], 0, 0, 0);
                    cr[cf][pf]  = __builtin_amdgcn_mfma_f32_16x16x32_bf16(An, Bcur[pf][2 + ks], cr[cf][pf], 0, 0, 0);
                    ci2[cf][pf] = __builtin_amdgcn_mfma_f32_16x16x32_bf16(Ai, Bcur[pf][ks],     ci2[cf][pf], 0, 0, 0);
                    ci2[cf][pf] = __builtin_amdgcn_mfma_f32_16x16x32_bf16(Ar, Bcur[pf][2 + ks], ci2[cf][pf], 0, 0, 0);
                }
            }
        __builtin_amdgcn_s_setprio(0);

        if (ct == 2 && rt < 2) {     // A restage at rt boundary (next B already in flight)
            __syncthreads();
            stageA(rt + 1);
            __syncthreads();
        }
    }

    if (cog >= 4) {
        // v: store straight to vT [token][64] u32 -- 8 x uint4 per thread, no LDS
#pragma unroll
        for (int cf = 0; cf < 2; ++cf)
#pragma unroll
            for (int pf = 0; pf < 4; ++pf) {
                int token = row * 256 + wv * 64 + pf * 16 + l15;
                int e0 = (cog - 4) * 32 + 16 * cf + 4 * l4;
                uint4 vv = make_uint4(pack2(cr[cf][pf][0], ci2[cf][pf][0]),
                                      pack2(cr[cf][pf][1], ci2[cf][pf][1]),
                                      pack2(cr[cf][pf][2], ci2[cf][pf][2]),
                                      pack2(cr[cf][pf][3], ci2[cf][pf][3]));
                *(uint4*)&vT[(size_t)token * 64 + e0] = vv;
            }
        return;
    }

    // ---------- q,k epilogue: LDS transpose -> wide coalesced stores ----------
    __syncthreads();
#pragma unroll
    for (int cf = 0; cf < 2; ++cf)
#pragma unroll
        for (int pf = 0; pf < 4; ++pf)
#pragma unroll
            for (int r = 0; r < 4; ++r) {
                int col = 16 * cf + 4 * l4 + r;          // local co 0..31
                int tok = wv * 64 + pf * 16 + l15;       // local token 0..255
                Tep[col * 257 + tok] = pack2(cr[cf][pf][r], ci2[cf][pf][r]);
            }
    __syncthreads();

    const int co_l = t & 31, seg = (t >> 5) << 5;
    u32 vb[32];
#pragma unroll
    for (int j = 0; j < 32; ++j) vb[j] = Tep[co_l * 257 + seg + j];
    const int token0 = row * 256 + seg;

    int co = cog * 32 + co_l;
    int pl = (co < 64) ? 0 : 2;
    int c2 = co & 63;
    u32 rw[16], iw[16];
#pragma unroll
    for (int j = 0; j < 16; ++j) {
        rw[j] = (vb[2 * j] & 0xFFFFu) | (vb[2 * j + 1] << 16);
        iw[j] = (vb[2 * j] >> 16) | (vb[2 * j + 1] & 0xFFFF0000u);
    }
    uint4* dr_ = (uint4*)&dwp[(size_t)(pl * 64 + c2) * HWS + token0];
    uint4* di_ = (uint4*)&dwp[(size_t)((pl + 1) * 64 + c2) * HWS + token0];
#pragma unroll
    for (int j = 0; j < 4; ++j) {
        dr_[j] = make_uint4(rw[4 * j], rw[4 * j + 1], rw[4 * j + 2], rw[4 * j + 3]);
        di_[j] = make_uint4(iw[4 * j], iw[4 * j + 1], iw[4 * j + 2], iw[4 * j + 3]);
    }
}

// ---------------- Kernel C2: q k^T + fused sumsq via MFMA (no LDS) ----------------
__global__ __launch_bounds__(256) void k_qk(const u16* __restrict__ dwp,
                                            float* __restrict__ rnsum,
                                            float* __restrict__ attn,
                                            int b, int SP) {
    const int chunk = blockIdx.x;        // 0..31
    const int d = blockIdx.y;
    const int Kc = SP >> 5;
    const int kc0 = chunk * Kc;
    const u16* qp = dwp + (size_t)d * 64 * SP;
    const u16* kp = dwp + (size_t)(2 + d) * 64 * SP;

    const int t = threadIdx.x, lane = t & 63, wid = t >> 6;
    const int wy = wid >> 1, wx = wid & 1;
    const int l15 = lane & 15, l4 = lane >> 4;

    f32x4 zz = {0.f, 0.f, 0.f, 0.f};
    f32x4 acc[2][2] = {{zz, zz}, {zz, zz}};
    float sq[2] = {0.f, 0.f}, sk[2] = {0.f, 0.f};

    const int iters = Kc >> 5;
    for (int ks = 0; ks < iters; ++ks) {
        int k0 = kc0 + ks * 32 + 8 * l4;
        bf16x8 aq[2], bk[2];
#pragma unroll
        for (int cf = 0; cf < 2; ++cf)
            aq[cf] = *(const bf16x8*)&qp[(size_t)(32 * wy + 16 * cf + l15) * SP + k0];
#pragma unroll
        for (int ef = 0; ef < 2; ++ef)
            bk[ef] = *(const bf16x8*)&kp[(size_t)(32 * wx + 16 * ef + l15) * SP + k0];

        if (wx == 0)
#pragma unroll
            for (int cf = 0; cf < 2; ++cf)
#pragma unroll
                for (int j = 0; j < 8; ++j) {
                    float f = bf2f((u16)aq[cf][j]);
                    sq[cf] = fmaf(f, f, sq[cf]);
                }
        if (wy == 0)
#pragma unroll
            for (int ef = 0; ef < 2; ++ef)
#pragma unroll
                for (int j = 0; j < 8; ++j) {
                    float f = bf2f((u16)bk[ef][j]);
                    sk[ef] = fmaf(f, f, sk[ef]);
                }

#pragma unroll
        for (int cf = 0; cf < 2; ++cf)
#pragma unroll
            for (int ef = 0; ef < 2; ++ef)
                acc[cf][ef] = __builtin_amdgcn_mfma_f32_16x16x32_bf16(aq[cf], bk[ef], acc[cf][ef], 0, 0, 0);
    }

#pragma unroll
    for (int cf = 0; cf < 2; ++cf)
#pragma unroll
        for (int ef = 0; ef < 2; ++ef)
#pragma unroll
            for (int r = 0; r < 4; ++r) {
                int cq = 32 * wy + 16 * cf + 4 * l4 + r;
                int ce = 32 * wx + 16 * ef + l15;
                atomicAdd(&attn[((b * 2 + d) * 64 + cq) * 64 + ce], acc[cf][ef][r]);
            }

    if (wx == 0)
#pragma unroll
        for (int cf = 0; cf < 2; ++cf) {
            float v = sq[cf];
            v += __shfl_xor(v, 16);
            v += __shfl_xor(v, 32);
            if (lane < 16)
                atomicAdd(&rnsum[((size_t)b * 128 + 32 * wy + 16 * cf + lane) * 2 + d], v);
        }
    if (wy == 0)
#pragma unroll
        for (int ef = 0; ef < 2; ++ef) {
            float v = sk[ef];
            v += __shfl_xor(v, 16);
            v += __shfl_xor(v, 32);
            if (lane < 16)
                atomicAdd(&rnsum[((size_t)b * 128 + 64 + 32 * wx + 16 * ef + lane) * 2 + d], v);
        }
}

// ---------------- Kernel D1: scale + row softmax -> P ----------------
__global__ __launch_bounds__(64) void k_prob(const float* __restrict__ attn,
                                             const float* __restrict__ rnsum,
                                             float* __restrict__ P, int b) {
    int d = blockIdx.x;
    int t = threadIdx.x;
    __shared__ float rks[64];
    float sk = rnsum[((size_t)b * 128 + 64 + t) * 2 + d];
    rks[t] = 1.0f / fmaxf(sqrtf(sk), 1e-12f);
    float sq = rnsum[((size_t)b * 128 + t) * 2 + d];
    float rq = 1.0f / fmaxf(sqrtf(sq), 1e-12f);
    __syncthreads();

    const float* arow = attn + ((size_t)(b * 2 + d) * 64 + t) * 64;
    float v[64];
    float m = -1e30f;
#pragma unroll
    for (int e = 0; e < 64; ++e) { v[e] = arow[e] * rq * rks[e]; m = fmaxf(m, v[e]); }
    float ssum = 0.f;
#pragma unroll
    for (int e = 0; e < 64; ++e) { v[e] = __expf(v[e] - m); ssum += v[e]; }
    float r = 1.0f / ssum;
    float* prow = P + ((size_t)(b * 2 + d) * 64 + t) * 64;
#pragma unroll
    for (int e = 0; e < 64; ++e) prow[e] = v[e] * r;
}

// ---------------- Kernel D2: build A_big from P and proj weights ----------------
__global__ __launch_bounds__(256) void k_M(const float* __restrict__ P,
                                           const float* __restrict__ pwr,
                                           const float* __restrict__ pwi,
                                           u16* __restrict__ Abig, int b) {
    int pair = blockIdx.x * 256 + threadIdx.x;   // 0..4095
    __shared__ float P0[64][64], P1[64][64];
    __shared__ float Wr[64][64], Wi2[64][64];
    for (int i = threadIdx.x; i < 4096; i += 256) {
        P0[i >> 6][i & 63] = P[(size_t)(b * 2 + 0) * 4096 + i];
        P1[i >> 6][i & 63] = P[(size_t)(b * 2 + 1) * 4096 + i];
        Wr[i >> 6][i & 63] = pwr[i];
        Wi2[i >> 6][i & 63] = pwi[i];
    }
    __syncthreads();
    int co = pair >> 6, e = pair & 63;
    float m1 = 0.f, m2 = 0.f, m3 = 0.f, m4 = 0.f;
#pragma unroll 8
    for (int c = 0; c < 64; ++c) {
        float pr = Wr[co][c], pi = Wi2[co][c];
        float a0 = P0[c][e], a1 = P1[c][e];
        m1 = fmaf(pr, a0, m1);
        m2 = fmaf(pi, a1, m2);
        m3 = fmaf(pr, a1, m3);
        m4 = fmaf(pi, a0, m4);
    }
    u16* AB = Abig + (size_t)b * 16384;
    AB[(2 * co) * 128 + 2 * e]         = f2bf(m1);
    AB[(2 * co) * 128 + 2 * e + 1]     = f2bf(-m2);
    AB[(2 * co + 1) * 128 + 2 * e]     = f2bf(m4);
    AB[(2 * co + 1) * 128 + 2 * e + 1] = f2bf(m3);
}

// ---------------- Kernel F: out = A_big * vT via MFMA (no LDS) ----------------
__global__ __launch_bounds__(256) void k_out(const u16* __restrict__ Abig,
                                             const u16* __restrict__ vT,
                                             float* __restrict__ outb) {
    const int p0 = blockIdx.x << 6;
    const int t = threadIdx.x, lane = t & 63, w = t >> 6;
    const int l15 = lane & 15, l4 = lane >> 4;

    bf16x8 Af[2][4];
#pragma unroll
    for (int cf = 0; cf < 2; ++cf)
#pragma unroll
        for (int ks = 0; ks < 4; ++ks)
            Af[cf][ks] = *(const bf16x8*)&Abig[(size_t)(32 * w + 16 * cf + l15) * 128 + 32 * ks + 8 * l4];

    f32x4 zz = {0.f, 0.f, 0.f, 0.f};
    f32x4 acc[2][4];
#pragma unroll
    for (int cf = 0; cf < 2; ++cf)
#pragma unroll
        for (int nf = 0; nf < 4; ++nf) acc[cf][nf] = zz;

#pragma unroll
    for (int ks = 0; ks < 4; ++ks) {
        bf16x8 Bf[4];
#pragma unroll
        for (int nf = 0; nf < 4; ++nf)
            Bf[nf] = *(const bf16x8*)&vT[(size_t)(p0 + 16 * nf + l15) * 128 + 32 * ks + 8 * l4];
#pragma unroll
        for (int cf = 0; cf < 2; ++cf)
#pragma unroll
            for (int nf = 0; nf < 4; ++nf)
                acc[cf][nf] = __builtin_amdgcn_mfma_f32_16x16x32_bf16(Af[cf][ks], Bf[nf], acc[cf][nf], 0, 0, 0);
    }

    float2* o2 = (float2*)outb;
#pragma unroll
    for (int cf = 0; cf < 2; ++cf)
#pragma unroll
        for (int nf = 0; nf < 4; ++nf) {
            int co = 16 * w + 8 * cf + 2 * l4;
            int p = p0 + 16 * nf + l15;
            o2[(size_t)co * HWS + p]       = make_float2(acc[cf][nf][0], acc[cf][nf][1]);
            o2[(size_t)(co + 1) * HWS + p] = make_float2(acc[cf][nf][2], acc[cf][nf][3]);
        }
}

extern "C" void kernel_launch(void* const* d_in, const int* in_sizes, int n_in,
                              void* d_out, int out_size, void* d_ws, size_t ws_size,
                              hipStream_t stream) {
    const float* x      = (const float*)d_in[0];
    const float* qkv_wr = (const float*)d_in[1];
    const float* qkv_wi = (const float*)d_in[2];
    const float* dw_wr  = (const float*)d_in[3];
    const float* dw_wi  = (const float*)d_in[4];
    const float* p_wr   = (const float*)d_in[5];
    const float* p_wi   = (const float*)d_in[6];
    float* out = (float*)d_out;

    // workspace (~68.1 MB)
    char* base = (char*)d_ws;
    const size_t xt_sz = (size_t)PIT * PIT * 64 * 2;       // 8,520,192 B per plane
    u16*   dwp  = (u16*)base;                              // 33,554,432 B
    u16*   xTr  = (u16*)(base + 33554432);
    u16*   xTi  = (u16*)(base + 33554432 + xt_sz);
    u32*   vT   = (u32*)(base + 33554432 + 2 * xt_sz);     // 16,777,216 B
    u16*   WB   = (u16*)(base + 33554432 + 2 * xt_sz + 16777216);   // 663,552 B
    float* rnsum = (float*)((char*)WB + 663552);
    float* attn  = rnsum + 512;
    float* Pbuf  = attn + 16384;
    u16*   Abig  = (u16*)(Pbuf + 16384);

    k_fold<<<432, 256, 0, stream>>>(qkv_wr, qkv_wi, dw_wr, dw_wi, WB);
    k_zero<<<66, 256, 0, stream>>>(rnsum, 512 + 16384);
    k_border<<<33, 256, 0, stream>>>(xTr, xTi);

    for (int b = 0; b < 2; ++b) {
        const float* xb = x + (size_t)b * 64 * HWS * 2;
        k_xt<<<1024, 256, 0, stream>>>(xb, xTr, xTi);
        k_conv<<<1536, 256, 0, stream>>>(xTr, xTi, WB, dwp, vT);
        k_qk<<<dim3(32, 2), 256, 0, stream>>>(dwp, rnsum, attn, b, HWS);
        k_prob<<<2, 64, 0, stream>>>(attn, rnsum, Pbuf, b);
        k_M<<<16, 256, 0, stream>>>(Pbuf, p_wr, p_wi, Abig, b);
        k_out<<<1024, 256, 0, stream>>>(Abig + (size_t)b * 16384, (const u16*)vT,
                                        out + (size_t)b * 64 * HWS * 2);
    }
}

// Round 13
// 284.823 us; speedup vs baseline: 1.6958x; 1.6958x over previous
//
#include <hip/hip_runtime.h>

#define HWS 65536   // 256*256
#define SPZ 66048   // (256+2)*256 halo strip positions

typedef __attribute__((ext_vector_type(8))) short bf16x8;
typedef __attribute__((ext_vector_type(4))) float f32x4;
typedef unsigned int u32;
typedef unsigned short u16;

__device__ __forceinline__ u16 f2bf(float x) {
    u32 u = __float_as_uint(x);
    return (u16)((u + 0x7fffu + ((u >> 16) & 1u)) >> 16);
}
__device__ __forceinline__ float bf2f(u32 h) { return __uint_as_float(h << 16); }
__device__ __forceinline__ u32 pack2(float a, float b) {
    return (u32)f2bf(a) | ((u32)f2bf(b) << 16);
}

// ---------------- tiny helpers ----------------
__global__ void k_zero(float* __restrict__ p, int n) {
    int i = blockIdx.x * 256 + threadIdx.x;
    if (i < n) p[i] = 0.f;
}

// convert qkv weights to bf16 planes: [Wr | Wi | -Wi], each [192][64]
__global__ void k_wcvt(const float* __restrict__ wr, const float* __restrict__ wi,
                       u16* __restrict__ wbf) {
    int i = blockIdx.x * 256 + threadIdx.x;
    if (i < 12288) {
        wbf[i]         = f2bf(wr[i]);
        wbf[12288 + i] = f2bf(wi[i]);
        wbf[24576 + i] = f2bf(-wi[i]);
    }
}

// ---------------- Kernel X: transpose+convert x -> xTr/xTi bf16 [HWS][64] ----------------
__global__ __launch_bounds__(256) void k_xt(const float* __restrict__ x,
                                            u16* __restrict__ xTr,
                                            u16* __restrict__ xTi) {
    __shared__ u16 Tr[64][73], Ti[64][73];
    int p0 = blockIdx.x << 6;
    int t = threadIdx.x;
    const float2* x2 = (const float2*)x;
    for (int i = t; i < 4096; i += 256) {
        int ci = i >> 6, c = i & 63;
        float2 v = x2[(size_t)ci * HWS + p0 + c];
        Tr[c][ci] = f2bf(v.x);
        Ti[c][ci] = f2bf(v.y);
    }
    __syncthreads();
    for (int i = t; i < 4096; i += 256) {
        int rr = i >> 6, ci = i & 63;
        xTr[(size_t)(p0 + rr) * 64 + ci] = Tr[rr][ci];
        xTi[(size_t)(p0 + rr) * 64 + ci] = Ti[rr][ci];
    }
}

// ---------------- Kernel A: qkv 1x1 complex conv, global->MFMA, no LDS ----------------
// xTr/xTi: [HWS][64] bf16; wbf planes [192][64]; qs: [192][SPZ] packed bf16 (r,i)
// grid (6 cog, 258 row-tiles); 4 waves, each wave 64 positions of the row.
__global__ __launch_bounds__(256) void k_qkv(const u16* __restrict__ xTr,
                                             const u16* __restrict__ xTi,
                                             const u16* __restrict__ wbf,
                                             u32* __restrict__ qs) {
    const int cog = blockIdx.x;          // 0..5, 32 co each
    const int rt  = blockIdx.y;          // 0..257
    const int w   = rt - 1;              // image row (may be OOB -> zeros)
    const int t = threadIdx.x, lane = t & 63, wv = t >> 6;
    const int l15 = lane & 15, l4 = lane >> 4;
    const bool valid = (unsigned)w < 256u;

    bf16x8 Ar[2][2], Ai[2][2], An[2][2];
#pragma unroll
    for (int cf = 0; cf < 2; ++cf)
#pragma unroll
        for (int ks = 0; ks < 2; ++ks) {
            size_t off = (size_t)(cog * 32 + 16 * cf + l15) * 64 + 32 * ks + 8 * l4;
            Ar[cf][ks] = *(const bf16x8*)&wbf[off];
            Ai[cf][ks] = *(const bf16x8*)&wbf[12288 + off];
            An[cf][ks] = *(const bf16x8*)&wbf[24576 + off];
        }

    const f32x4 zz = {0.f, 0.f, 0.f, 0.f};
#pragma unroll
    for (int pf = 0; pf < 4; ++pf) {
        f32x4 cr[2] = {zz, zz}, cim[2] = {zz, zz};
        if (valid) {
            bf16x8 br[2], bi[2];
#pragma unroll
            for (int ks = 0; ks < 2; ++ks) {
                size_t boff = (size_t)(w * 256 + wv * 64 + pf * 16 + l15) * 64
                              + 32 * ks + 8 * l4;
                br[ks] = *(const bf16x8*)&xTr[boff];
                bi[ks] = *(const bf16x8*)&xTi[boff];
            }
#pragma unroll
            for (int ks = 0; ks < 2; ++ks)
#pragma unroll
                for (int cf = 0; cf < 2; ++cf) {
                    cr[cf]  = __builtin_amdgcn_mfma_f32_16x16x32_bf16(Ar[cf][ks], br[ks], cr[cf], 0, 0, 0);
                    cr[cf]  = __builtin_amdgcn_mfma_f32_16x16x32_bf16(An[cf][ks], bi[ks], cr[cf], 0, 0, 0);
                    cim[cf] = __builtin_amdgcn_mfma_f32_16x16x32_bf16(Ai[cf][ks], br[ks], cim[cf], 0, 0, 0);
                    cim[cf] = __builtin_amdgcn_mfma_f32_16x16x32_bf16(Ar[cf][ks], bi[ks], cim[cf], 0, 0, 0);
                }
        }
        int p = rt * 256 + wv * 64 + pf * 16 + l15;
#pragma unroll
        for (int cf = 0; cf < 2; ++cf)
#pragma unroll
            for (int r = 0; r < 4; ++r) {
                int co = cog * 32 + 16 * cf + 4 * l4 + r;
                qs[(size_t)co * SPZ + p] = valid ? pack2(cr[cf][r], cim[cf][r]) : 0u;
            }
    }
}

// ---------------- Kernel B: depthwise 3x3 complex conv, 4 pixels/thread ----------------
// qs packed [192][SPZ]; ch<128 -> dwp planes [4][64][HWS] u16 (q_r,q_i,k_r,k_i);
// ch>=128 -> vpack [64][HWS] u32 (r,i) inside d_out batch region
__global__ __launch_bounds__(256) void k_dw(const u32* __restrict__ qs,
                                            const float* __restrict__ wr,
                                            const float* __restrict__ wi,
                                            u16* __restrict__ dwp,
                                            u32* __restrict__ vpack) {
    int idx = blockIdx.x * 256 + threadIdx.x;   // over 192*HWS/4
    int p4 = (idx & (HWS / 4 - 1)) << 2;        // 4 consecutive h
    int ch = idx >> 14;
    int r = p4 >> 8, h = p4 & 255;              // h in {0,4,...,252}
    const u32* src = qs + (size_t)ch * SPZ + r * 256;

    float wrl[9], wil[9];
#pragma unroll
    for (int tt = 0; tt < 9; ++tt) { wrl[tt] = wr[ch * 9 + tt]; wil[tt] = wi[ch * 9 + tt]; }

    // batched loads: 3 rows x 6 cols (h-1 .. h+4), zeros at image h-border
    u32 uv[3][6];
#pragma unroll
    for (int du = 0; du < 3; ++du)
#pragma unroll
        for (int j = 0; j < 6; ++j) {
            int hh = h - 1 + j;
            uv[du][j] = ((unsigned)hh < 256u) ? src[du * 256 + hh] : 0u;
        }
    float vr[3][6], vi[3][6];
#pragma unroll
    for (int du = 0; du < 3; ++du)
#pragma unroll
        for (int j = 0; j < 6; ++j) {
            vr[du][j] = bf2f(uv[du][j] & 0xffffu);
            vi[du][j] = bf2f(uv[du][j] >> 16);
        }

    float ar[4] = {0.f, 0.f, 0.f, 0.f}, ai[4] = {0.f, 0.f, 0.f, 0.f};
#pragma unroll
    for (int du = 0; du < 3; ++du)
#pragma unroll
        for (int ct = 0; ct < 3; ++ct) {
            float w0 = wrl[du * 3 + ct], w1 = wil[du * 3 + ct];
#pragma unroll
            for (int px = 0; px < 4; ++px) {
                float xr = vr[du][px + ct], xi = vi[du][px + ct];
                ar[px] = fmaf(w0, xr, ar[px]); ar[px] = fmaf(-w1, xi, ar[px]);
                ai[px] = fmaf(w1, xr, ai[px]); ai[px] = fmaf(w0, xi, ai[px]);
            }
        }

    if (ch < 128) {
        int pl = (ch < 64) ? 0 : 2;
        int c2 = ch & 63;
        uint2 rw = make_uint2(pack2(ar[0], ar[1]), pack2(ar[2], ar[3]));
        uint2 iw = make_uint2(pack2(ai[0], ai[1]), pack2(ai[2], ai[3]));
        *(uint2*)&dwp[(size_t)(pl * 64 + c2) * HWS + p4] = rw;
        *(uint2*)&dwp[(size_t)((pl + 1) * 64 + c2) * HWS + p4] = iw;
    } else {
        int e = ch - 128;
        uint4 vv = make_uint4(pack2(ar[0], ai[0]), pack2(ar[1], ai[1]),
                              pack2(ar[2], ai[2]), pack2(ar[3], ai[3]));
        *(uint4*)&vpack[(size_t)e * HWS + p4] = vv;
    }
}

// ---------------- Kernel C: q k^T + fused sumsq via MFMA (no LDS) ----------------
__global__ __launch_bounds__(256) void k_qk(const u16* __restrict__ dwp,
                                            float* __restrict__ rnsum,
                                            float* __restrict__ attn,
                                            int b, int SP) {
    const int chunk = blockIdx.x;        // 0..31
    const int d = blockIdx.y;
    const int Kc = SP >> 5;
    const int kc0 = chunk * Kc;
    const u16* qp = dwp + (size_t)d * 64 * SP;
    const u16* kp = dwp + (size_t)(2 + d) * 64 * SP;

    const int t = threadIdx.x, lane = t & 63, wid = t >> 6;
    const int wy = wid >> 1, wx = wid & 1;
    const int l15 = lane & 15, l4 = lane >> 4;

    f32x4 zz = {0.f, 0.f, 0.f, 0.f};
    f32x4 acc[2][2] = {{zz, zz}, {zz, zz}};
    float sq[2] = {0.f, 0.f}, sk[2] = {0.f, 0.f};

    const int iters = Kc >> 5;
    for (int ks = 0; ks < iters; ++ks) {
        int k0 = kc0 + ks * 32 + 8 * l4;
        bf16x8 aq[2], bk[2];
#pragma unroll
        for (int cf = 0; cf < 2; ++cf)
            aq[cf] = *(const bf16x8*)&qp[(size_t)(32 * wy + 16 * cf + l15) * SP + k0];
#pragma unroll
        for (int ef = 0; ef < 2; ++ef)
            bk[ef] = *(const bf16x8*)&kp[(size_t)(32 * wx + 16 * ef + l15) * SP + k0];

        if (wx == 0)
#pragma unroll
            for (int cf = 0; cf < 2; ++cf)
#pragma unroll
                for (int j = 0; j < 8; ++j) {
                    float f = bf2f((u16)aq[cf][j]);
                    sq[cf] = fmaf(f, f, sq[cf]);
                }
        if (wy == 0)
#pragma unroll
            for (int ef = 0; ef < 2; ++ef)
#pragma unroll
                for (int j = 0; j < 8; ++j) {
                    float f = bf2f((u16)bk[ef][j]);
                    sk[ef] = fmaf(f, f, sk[ef]);
                }

#pragma unroll
        for (int cf = 0; cf < 2; ++cf)
#pragma unroll
            for (int ef = 0; ef < 2; ++ef)
                acc[cf][ef] = __builtin_amdgcn_mfma_f32_16x16x32_bf16(aq[cf], bk[ef], acc[cf][ef], 0, 0, 0);
    }

#pragma unroll
    for (int cf = 0; cf < 2; ++cf)
#pragma unroll
        for (int ef = 0; ef < 2; ++ef)
#pragma unroll
            for (int r = 0; r < 4; ++r) {
                int cq = 32 * wy + 16 * cf + 4 * l4 + r;
                int ce = 32 * wx + 16 * ef + l15;
                atomicAdd(&attn[((b * 2 + d) * 64 + cq) * 64 + ce], acc[cf][ef][r]);
            }

    if (wx == 0)
#pragma unroll
        for (int cf = 0; cf < 2; ++cf) {
            float v = sq[cf];
            v += __shfl_xor(v, 16);
            v += __shfl_xor(v, 32);
            if (lane < 16)
                atomicAdd(&rnsum[((size_t)b * 128 + 32 * wy + 16 * cf + lane) * 2 + d], v);
        }
    if (wy == 0)
#pragma unroll
        for (int ef = 0; ef < 2; ++ef) {
            float v = sk[ef];
            v += __shfl_xor(v, 16);
            v += __shfl_xor(v, 32);
            if (lane < 16)
                atomicAdd(&rnsum[((size_t)b * 128 + 64 + 32 * wx + 16 * ef + lane) * 2 + d], v);
        }
}

// ---------------- Kernel D1: scale + row softmax -> P (grid (2b,2d), 64 thr) ----------------
__global__ __launch_bounds__(64) void k_prob(const float* __restrict__ attn,
                                             const float* __restrict__ rnsum,
                                             float* __restrict__ P) {
    int b = blockIdx.x, d = blockIdx.y;
    int t = threadIdx.x;
    __shared__ float rks[64];
    float sk = rnsum[((size_t)b * 128 + 64 + t) * 2 + d];
    rks[t] = 1.0f / fmaxf(sqrtf(sk), 1e-12f);
    float sq = rnsum[((size_t)b * 128 + t) * 2 + d];
    float rq = 1.0f / fmaxf(sqrtf(sq), 1e-12f);
    __syncthreads();

    const float* arow = attn + ((size_t)(b * 2 + d) * 64 + t) * 64;
    float v[64];
    float m = -1e30f;
#pragma unroll
    for (int e = 0; e < 64; ++e) { v[e] = arow[e] * rq * rks[e]; m = fmaxf(m, v[e]); }
    float ssum = 0.f;
#pragma unroll
    for (int e = 0; e < 64; ++e) { v[e] = __expf(v[e] - m); ssum += v[e]; }
    float r = 1.0f / ssum;
    float* prow = P + ((size_t)(b * 2 + d) * 64 + t) * 64;
#pragma unroll
    for (int e = 0; e < 64; ++e) prow[e] = v[e] * r;
}

// ---------------- Kernel D2: build A_big from P and proj weights ----------------
// grid (16, 2b), 256 thr
__global__ __launch_bounds__(256) void k_M(const float* __restrict__ P,
                                           const float* __restrict__ pwr,
                                           const float* __restrict__ pwi,
                                           u16* __restrict__ Abig) {
    int b = blockIdx.y;
    int pair = blockIdx.x * 256 + threadIdx.x;   // 0..4095
    __shared__ float P0[64][64], P1[64][64];
    __shared__ float Wr[64][64], Wi2[64][64];
    for (int i = threadIdx.x; i < 4096; i += 256) {
        P0[i >> 6][i & 63] = P[(size_t)(b * 2 + 0) * 4096 + i];
        P1[i >> 6][i & 63] = P[(size_t)(b * 2 + 1) * 4096 + i];
        Wr[i >> 6][i & 63] = pwr[i];
        Wi2[i >> 6][i & 63] = pwi[i];
    }
    __syncthreads();
    int co = pair >> 6, e = pair & 63;
    float m1 = 0.f, m2 = 0.f, m3 = 0.f, m4 = 0.f;
#pragma unroll 8
    for (int c = 0; c < 64; ++c) {
        float pr = Wr[co][c], pi = Wi2[co][c];
        float a0 = P0[c][e], a1 = P1[c][e];
        m1 = fmaf(pr, a0, m1);
        m2 = fmaf(pi, a1, m2);
        m3 = fmaf(pr, a1, m3);
        m4 = fmaf(pi, a0, m4);
    }
    u16* AB = Abig + (size_t)b * 16384;
    AB[(2 * co) * 128 + 2 * e]         = f2bf(m1);
    AB[(2 * co) * 128 + 2 * e + 1]     = f2bf(-m2);
    AB[(2 * co + 1) * 128 + 2 * e]     = f2bf(m4);
    AB[(2 * co + 1) * 128 + 2 * e + 1] = f2bf(m3);
}

// ---------------- Kernel E: transpose vpack [64][HWS] u32 -> vT [HWS][64] u32 ----------------
__global__ __launch_bounds__(256) void k_vt(const u32* __restrict__ in,
                                            u32* __restrict__ outp) {
    __shared__ u32 tile[64][65];
    int p0 = blockIdx.x << 6;
    int t = threadIdx.x;
    for (int i = t; i < 4096; i += 256) {
        int e = i >> 6, c = i & 63;
        tile[e][c] = in[(size_t)e * HWS + p0 + c];
    }
    __syncthreads();
    for (int i = t; i < 4096; i += 256) {
        int r = i >> 6, e = i & 63;
        outp[(size_t)(p0 + r) * 64 + e] = tile[e][r];
    }
}

// ---------------- Kernel F: out = A_big * vT via MFMA (no LDS) ----------------
__global__ __launch_bounds__(256) void k_out(const u16* __restrict__ Abig,
                                             const u16* __restrict__ vT,
                                             float* __restrict__ outb) {
    const int p0 = blockIdx.x << 6;
    const int t = threadIdx.x, lane = t & 63, w = t >> 6;
    const int l15 = lane & 15, l4 = lane >> 4;

    bf16x8 Af[2][4];
#pragma unroll
    for (int cf = 0; cf < 2; ++cf)
#pragma unroll
        for (int ks = 0; ks < 4; ++ks)
            Af[cf][ks] = *(const bf16x8*)&Abig[(size_t)(32 * w + 16 * cf + l15) * 128 + 32 * ks + 8 * l4];

    f32x4 zz = {0.f, 0.f, 0.f, 0.f};
    f32x4 acc[2][4];
#pragma unroll
    for (int cf = 0; cf < 2; ++cf)
#pragma unroll
        for (int nf = 0; nf < 4; ++nf) acc[cf][nf] = zz;

#pragma unroll
    for (int ks = 0; ks < 4; ++ks) {
        bf16x8 Bf[4];
#pragma unroll
        for (int nf = 0; nf < 4; ++nf)
            Bf[nf] = *(const bf16x8*)&vT[(size_t)(p0 + 16 * nf + l15) * 128 + 32 * ks + 8 * l4];
#pragma unroll
        for (int cf = 0; cf < 2; ++cf)
#pragma unroll
            for (int nf = 0; nf < 4; ++nf)
                acc[cf][nf] = __builtin_amdgcn_mfma_f32_16x16x32_bf16(Af[cf][ks], Bf[nf], acc[cf][nf], 0, 0, 0);
    }

    float2* o2 = (float2*)outb;
#pragma unroll
    for (int cf = 0; cf < 2; ++cf)
#pragma unroll
        for (int nf = 0; nf < 4; ++nf) {
            int co = 16 * w + 8 * cf + 2 * l4;
            int p = p0 + 16 * nf + l15;
            o2[(size_t)co * HWS + p]       = make_float2(acc[cf][nf][0], acc[cf][nf][1]);
            o2[(size_t)(co + 1) * HWS + p] = make_float2(acc[cf][nf][2], acc[cf][nf][3]);
        }
}

extern "C" void kernel_launch(void* const* d_in, const int* in_sizes, int n_in,
                              void* d_out, int out_size, void* d_ws, size_t ws_size,
                              hipStream_t stream) {
    const float* x      = (const float*)d_in[0];
    const float* qkv_wr = (const float*)d_in[1];
    const float* qkv_wi = (const float*)d_in[2];
    const float* dw_wr  = (const float*)d_in[3];
    const float* dw_wi  = (const float*)d_in[4];
    const float* p_wr   = (const float*)d_in[5];
    const float* p_wi   = (const float*)d_in[6];
    float* out = (float*)d_out;

    // workspace layout (~101.3 MB; round-6 R=256 path proved ws_size >= 104 MB)
    char* base = (char*)d_ws;
    u32*   qs_u = (u32*)base;                               // 192*SPZ*4      = 50,724,864 B
    u16*   dwp  = (u16*)(base + 50724864);                  // 33,554,432 B
    u32*   vT   = (u32*)(base + 50724864 + 33554432);       // 16,777,216 B (xT during conv)
    u16*   xTr  = (u16*)vT;
    u16*   xTi  = xTr + (size_t)HWS * 64;
    u16*   wbf  = (u16*)(base + 50724864 + 33554432 + 16777216);   // 73,728 B
    float* rnsum = (float*)((char*)wbf + 73728);
    float* attn  = rnsum + 512;
    float* Pbuf  = attn + 16384;
    u16*   Abig  = (u16*)(Pbuf + 16384);

    k_wcvt<<<48, 256, 0, stream>>>(qkv_wr, qkv_wi, wbf);
    k_zero<<<66, 256, 0, stream>>>(rnsum, 512 + 16384);

    for (int b = 0; b < 2; ++b) {
        const float* xb = x + (size_t)b * 64 * HWS * 2;
        u32* vpack = (u32*)(out + (size_t)b * 64 * HWS * 2);   // scratch inside d_out
        k_xt<<<1024, 256, 0, stream>>>(xb, xTr, xTi);
        k_qkv<<<dim3(6, 258), 256, 0, stream>>>(xTr, xTi, wbf, qs_u);
        k_dw<<<192 * HWS / 4 / 256, 256, 0, stream>>>(qs_u, dw_wr, dw_wi, dwp, vpack);
        k_qk<<<dim3(32, 2), 256, 0, stream>>>(dwp, rnsum, attn, b, HWS);
    }
    k_prob<<<dim3(2, 2), 64, 0, stream>>>(attn, rnsum, Pbuf);
    k_M<<<dim3(16, 2), 256, 0, stream>>>(Pbuf, p_wr, p_wi, Abig);
    for (int b = 0; b < 2; ++b) {
        u32* vpack = (u32*)(out + (size_t)b * 64 * HWS * 2);
        k_vt<<<1024, 256, 0, stream>>>(vpack, vT);
        k_out<<<1024, 256, 0, stream>>>(Abig + (size_t)b * 16384, (const u16*)vT,
                                        out + (size_t)b * 64 * HWS * 2);
    }
}

// Round 14
// 245.434 us; speedup vs baseline: 1.9680x; 1.1605x over previous
//
#include <hip/hip_runtime.h>

#define HWS 65536   // 256*256
#define SPZ 66048   // (256+2)*256 halo strip positions

typedef __attribute__((ext_vector_type(8))) short bf16x8;
typedef __attribute__((ext_vector_type(4))) float f32x4;
typedef unsigned int u32;
typedef unsigned short u16;

__device__ __forceinline__ u16 f2bf(float x) {
    u32 u = __float_as_uint(x);
    return (u16)((u + 0x7fffu + ((u >> 16) & 1u)) >> 16);
}
__device__ __forceinline__ float bf2f(u32 h) { return __uint_as_float(h << 16); }
__device__ __forceinline__ u32 pack2(float a, float b) {
    return (u32)f2bf(a) | ((u32)f2bf(b) << 16);
}

// ---------------- tiny helpers ----------------
__global__ void k_zero(float* __restrict__ p, int n) {
    int i = blockIdx.x * 256 + threadIdx.x;
    if (i < n) p[i] = 0.f;
}

// convert qkv weights to bf16 planes: [Wr | Wi | -Wi], each [192][64]
__global__ void k_wcvt(const float* __restrict__ wr, const float* __restrict__ wi,
                       u16* __restrict__ wbf) {
    int i = blockIdx.x * 256 + threadIdx.x;
    if (i < 12288) {
        wbf[i]         = f2bf(wr[i]);
        wbf[12288 + i] = f2bf(wi[i]);
        wbf[24576 + i] = f2bf(-wi[i]);
    }
}

// ---------------- Kernel X: transpose+convert x -> xTr/xTi bf16 [HWS][64] ----------------
__global__ __launch_bounds__(256) void k_xt(const float* __restrict__ x,
                                            u16* __restrict__ xTr,
                                            u16* __restrict__ xTi) {
    __shared__ u16 Tr[64][73], Ti[64][73];
    int p0 = blockIdx.x << 6;
    int t = threadIdx.x;
    const float2* x2 = (const float2*)x;
    for (int i = t; i < 4096; i += 256) {
        int ci = i >> 6, c = i & 63;
        float2 v = x2[(size_t)ci * HWS + p0 + c];
        Tr[c][ci] = f2bf(v.x);
        Ti[c][ci] = f2bf(v.y);
    }
    __syncthreads();
    for (int i = t; i < 4096; i += 256) {
        int rr = i >> 6, ci = i & 63;
        xTr[(size_t)(p0 + rr) * 64 + ci] = Tr[rr][ci];
        xTi[(size_t)(p0 + rr) * 64 + ci] = Ti[rr][ci];
    }
}

// ---------------- Kernel A: qkv 1x1 complex conv, global->MFMA, no LDS ----------------
__global__ __launch_bounds__(256) void k_qkv(const u16* __restrict__ xTr,
                                             const u16* __restrict__ xTi,
                                             const u16* __restrict__ wbf,
                                             u32* __restrict__ qs) {
    const int cog = blockIdx.x;          // 0..5, 32 co each
    const int rt  = blockIdx.y;          // 0..257
    const int w   = rt - 1;              // image row (may be OOB -> zeros)
    const int t = threadIdx.x, lane = t & 63, wv = t >> 6;
    const int l15 = lane & 15, l4 = lane >> 4;
    const bool valid = (unsigned)w < 256u;

    bf16x8 Ar[2][2], Ai[2][2], An[2][2];
#pragma unroll
    for (int cf = 0; cf < 2; ++cf)
#pragma unroll
        for (int ks = 0; ks < 2; ++ks) {
            size_t off = (size_t)(cog * 32 + 16 * cf + l15) * 64 + 32 * ks + 8 * l4;
            Ar[cf][ks] = *(const bf16x8*)&wbf[off];
            Ai[cf][ks] = *(const bf16x8*)&wbf[12288 + off];
            An[cf][ks] = *(const bf16x8*)&wbf[24576 + off];
        }

    const f32x4 zz = {0.f, 0.f, 0.f, 0.f};
#pragma unroll
    for (int pf = 0; pf < 4; ++pf) {
        f32x4 cr[2] = {zz, zz}, cim[2] = {zz, zz};
        if (valid) {
            bf16x8 br[2], bi[2];
#pragma unroll
            for (int ks = 0; ks < 2; ++ks) {
                size_t boff = (size_t)(w * 256 + wv * 64 + pf * 16 + l15) * 64
                              + 32 * ks + 8 * l4;
                br[ks] = *(const bf16x8*)&xTr[boff];
                bi[ks] = *(const bf16x8*)&xTi[boff];
            }
#pragma unroll
            for (int ks = 0; ks < 2; ++ks)
#pragma unroll
                for (int cf = 0; cf < 2; ++cf) {
                    cr[cf]  = __builtin_amdgcn_mfma_f32_16x16x32_bf16(Ar[cf][ks], br[ks], cr[cf], 0, 0, 0);
                    cr[cf]  = __builtin_amdgcn_mfma_f32_16x16x32_bf16(An[cf][ks], bi[ks], cr[cf], 0, 0, 0);
                    cim[cf] = __builtin_amdgcn_mfma_f32_16x16x32_bf16(Ai[cf][ks], br[ks], cim[cf], 0, 0, 0);
                    cim[cf] = __builtin_amdgcn_mfma_f32_16x16x32_bf16(Ar[cf][ks], bi[ks], cim[cf], 0, 0, 0);
                }
        }
        int p = rt * 256 + wv * 64 + pf * 16 + l15;
#pragma unroll
        for (int cf = 0; cf < 2; ++cf)
#pragma unroll
            for (int r = 0; r < 4; ++r) {
                int co = cog * 32 + 16 * cf + 4 * l4 + r;
                qs[(size_t)co * SPZ + p] = valid ? pack2(cr[cf][r], cim[cf][r]) : 0u;
            }
    }
}

// ---------------- Kernel B: depthwise 3x3 complex conv, 4 pixels/thread ----------------
__global__ __launch_bounds__(256) void k_dw(const u32* __restrict__ qs,
                                            const float* __restrict__ wr,
                                            const float* __restrict__ wi,
                                            u16* __restrict__ dwp,
                                            u32* __restrict__ vpack) {
    int idx = blockIdx.x * 256 + threadIdx.x;   // over 192*HWS/4
    int p4 = (idx & (HWS / 4 - 1)) << 2;        // 4 consecutive h
    int ch = idx >> 14;
    int r = p4 >> 8, h = p4 & 255;
    const u32* src = qs + (size_t)ch * SPZ + r * 256;

    float wrl[9], wil[9];
#pragma unroll
    for (int tt = 0; tt < 9; ++tt) { wrl[tt] = wr[ch * 9 + tt]; wil[tt] = wi[ch * 9 + tt]; }

    u32 uv[3][6];
#pragma unroll
    for (int du = 0; du < 3; ++du)
#pragma unroll
        for (int j = 0; j < 6; ++j) {
            int hh = h - 1 + j;
            uv[du][j] = ((unsigned)hh < 256u) ? src[du * 256 + hh] : 0u;
        }
    float vr[3][6], vi[3][6];
#pragma unroll
    for (int du = 0; du < 3; ++du)
#pragma unroll
        for (int j = 0; j < 6; ++j) {
            vr[du][j] = bf2f(uv[du][j] & 0xffffu);
            vi[du][j] = bf2f(uv[du][j] >> 16);
        }

    float ar[4] = {0.f, 0.f, 0.f, 0.f}, ai[4] = {0.f, 0.f, 0.f, 0.f};
#pragma unroll
    for (int du = 0; du < 3; ++du)
#pragma unroll
        for (int ct = 0; ct < 3; ++ct) {
            float w0 = wrl[du * 3 + ct], w1 = wil[du * 3 + ct];
#pragma unroll
            for (int px = 0; px < 4; ++px) {
                float xr = vr[du][px + ct], xi = vi[du][px + ct];
                ar[px] = fmaf(w0, xr, ar[px]); ar[px] = fmaf(-w1, xi, ar[px]);
                ai[px] = fmaf(w1, xr, ai[px]); ai[px] = fmaf(w0, xi, ai[px]);
            }
        }

    if (ch < 128) {
        int pl = (ch < 64) ? 0 : 2;
        int c2 = ch & 63;
        uint2 rw = make_uint2(pack2(ar[0], ar[1]), pack2(ar[2], ar[3]));
        uint2 iw = make_uint2(pack2(ai[0], ai[1]), pack2(ai[2], ai[3]));
        *(uint2*)&dwp[(size_t)(pl * 64 + c2) * HWS + p4] = rw;
        *(uint2*)&dwp[(size_t)((pl + 1) * 64 + c2) * HWS + p4] = iw;
    } else {
        int e = ch - 128;
        uint4 vv = make_uint4(pack2(ar[0], ai[0]), pack2(ar[1], ai[1]),
                              pack2(ar[2], ai[2]), pack2(ar[3], ai[3]));
        *(uint4*)&vpack[(size_t)e * HWS + p4] = vv;
    }
}

// ---------------- Kernel C: q k^T + fused sumsq via MFMA (no LDS) ----------------
// grid (64 chunks, 2 d); Kc = HWS/64
__global__ __launch_bounds__(256) void k_qk(const u16* __restrict__ dwp,
                                            float* __restrict__ rnsum,
                                            float* __restrict__ attn,
                                            int b, int SP) {
    const int chunk = blockIdx.x;        // 0..63
    const int d = blockIdx.y;
    const int Kc = SP >> 6;
    const int kc0 = chunk * Kc;
    const u16* qp = dwp + (size_t)d * 64 * SP;
    const u16* kp = dwp + (size_t)(2 + d) * 64 * SP;

    const int t = threadIdx.x, lane = t & 63, wid = t >> 6;
    const int wy = wid >> 1, wx = wid & 1;
    const int l15 = lane & 15, l4 = lane >> 4;

    f32x4 zz = {0.f, 0.f, 0.f, 0.f};
    f32x4 acc[2][2] = {{zz, zz}, {zz, zz}};
    float sq[2] = {0.f, 0.f}, sk[2] = {0.f, 0.f};

    const int iters = Kc >> 5;
    for (int ks = 0; ks < iters; ++ks) {
        int k0 = kc0 + ks * 32 + 8 * l4;
        bf16x8 aq[2], bk[2];
#pragma unroll
        for (int cf = 0; cf < 2; ++cf)
            aq[cf] = *(const bf16x8*)&qp[(size_t)(32 * wy + 16 * cf + l15) * SP + k0];
#pragma unroll
        for (int ef = 0; ef < 2; ++ef)
            bk[ef] = *(const bf16x8*)&kp[(size_t)(32 * wx + 16 * ef + l15) * SP + k0];

        if (wx == 0)
#pragma unroll
            for (int cf = 0; cf < 2; ++cf)
#pragma unroll
                for (int j = 0; j < 8; ++j) {
                    float f = bf2f((u16)aq[cf][j]);
                    sq[cf] = fmaf(f, f, sq[cf]);
                }
        if (wy == 0)
#pragma unroll
            for (int ef = 0; ef < 2; ++ef)
#pragma unroll
                for (int j = 0; j < 8; ++j) {
                    float f = bf2f((u16)bk[ef][j]);
                    sk[ef] = fmaf(f, f, sk[ef]);
                }

#pragma unroll
        for (int cf = 0; cf < 2; ++cf)
#pragma unroll
            for (int ef = 0; ef < 2; ++ef)
                acc[cf][ef] = __builtin_amdgcn_mfma_f32_16x16x32_bf16(aq[cf], bk[ef], acc[cf][ef], 0, 0, 0);
    }

#pragma unroll
    for (int cf = 0; cf < 2; ++cf)
#pragma unroll
        for (int ef = 0; ef < 2; ++ef)
#pragma unroll
            for (int r = 0; r < 4; ++r) {
                int cq = 32 * wy + 16 * cf + 4 * l4 + r;
                int ce = 32 * wx + 16 * ef + l15;
                atomicAdd(&attn[((b * 2 + d) * 64 + cq) * 64 + ce], acc[cf][ef][r]);
            }

    if (wx == 0)
#pragma unroll
        for (int cf = 0; cf < 2; ++cf) {
            float v = sq[cf];
            v += __shfl_xor(v, 16);
            v += __shfl_xor(v, 32);
            if (lane < 16)
                atomicAdd(&rnsum[((size_t)b * 128 + 32 * wy + 16 * cf + lane) * 2 + d], v);
        }
    if (wy == 0)
#pragma unroll
        for (int ef = 0; ef < 2; ++ef) {
            float v = sk[ef];
            v += __shfl_xor(v, 16);
            v += __shfl_xor(v, 32);
            if (lane < 16)
                atomicAdd(&rnsum[((size_t)b * 128 + 64 + 32 * wx + 16 * ef + lane) * 2 + d], v);
        }
}

// ---------------- Kernel D1: scale + row softmax -> P (grid 2 d, 64 thr) ----------------
__global__ __launch_bounds__(64) void k_prob(const float* __restrict__ attn,
                                             const float* __restrict__ rnsum,
                                             float* __restrict__ P, int b) {
    int d = blockIdx.x;
    int t = threadIdx.x;
    __shared__ float rks[64];
    float sk = rnsum[((size_t)b * 128 + 64 + t) * 2 + d];
    rks[t] = 1.0f / fmaxf(sqrtf(sk), 1e-12f);
    float sq = rnsum[((size_t)b * 128 + t) * 2 + d];
    float rq = 1.0f / fmaxf(sqrtf(sq), 1e-12f);
    __syncthreads();

    const float* arow = attn + ((size_t)(b * 2 + d) * 64 + t) * 64;
    float v[64];
    float m = -1e30f;
#pragma unroll
    for (int e = 0; e < 64; ++e) { v[e] = arow[e] * rq * rks[e]; m = fmaxf(m, v[e]); }
    float ssum = 0.f;
#pragma unroll
    for (int e = 0; e < 64; ++e) { v[e] = __expf(v[e] - m); ssum += v[e]; }
    float r = 1.0f / ssum;
    float* prow = P + ((size_t)(b * 2 + d) * 64 + t) * 64;
#pragma unroll
    for (int e = 0; e < 64; ++e) prow[e] = v[e] * r;
}

// ---------------- Kernel D2: build A_big from P and proj weights (grid 16, b param) ----------------
__global__ __launch_bounds__(256) void k_M(const float* __restrict__ P,
                                           const float* __restrict__ pwr,
                                           const float* __restrict__ pwi,
                                           u16* __restrict__ Abig, int b) {
    int pair = blockIdx.x * 256 + threadIdx.x;   // 0..4095
    __shared__ float P0[64][64], P1[64][64];
    __shared__ float Wr[64][64], Wi2[64][64];
    for (int i = threadIdx.x; i < 4096; i += 256) {
        P0[i >> 6][i & 63] = P[(size_t)(b * 2 + 0) * 4096 + i];
        P1[i >> 6][i & 63] = P[(size_t)(b * 2 + 1) * 4096 + i];
        Wr[i >> 6][i & 63] = pwr[i];
        Wi2[i >> 6][i & 63] = pwi[i];
    }
    __syncthreads();
    int co = pair >> 6, e = pair & 63;
    float m1 = 0.f, m2 = 0.f, m3 = 0.f, m4 = 0.f;
#pragma unroll 8
    for (int c = 0; c < 64; ++c) {
        float pr = Wr[co][c], pi = Wi2[co][c];
        float a0 = P0[c][e], a1 = P1[c][e];
        m1 = fmaf(pr, a0, m1);
        m2 = fmaf(pi, a1, m2);
        m3 = fmaf(pr, a1, m3);
        m4 = fmaf(pi, a0, m4);
    }
    u16* AB = Abig + (size_t)b * 16384;
    AB[(2 * co) * 128 + 2 * e]         = f2bf(m1);
    AB[(2 * co) * 128 + 2 * e + 1]     = f2bf(-m2);
    AB[(2 * co + 1) * 128 + 2 * e]     = f2bf(m4);
    AB[(2 * co + 1) * 128 + 2 * e + 1] = f2bf(m3);
}

// ---------------- Kernel E (fallback): transpose vpack [64][HWS] u32 -> vT [HWS][64] u32 ----------------
__global__ __launch_bounds__(256) void k_vt(const u32* __restrict__ in,
                                            u32* __restrict__ outp) {
    __shared__ u32 tile[64][65];
    int p0 = blockIdx.x << 6;
    int t = threadIdx.x;
    for (int i = t; i < 4096; i += 256) {
        int e = i >> 6, c = i & 63;
        tile[e][c] = in[(size_t)e * HWS + p0 + c];
    }
    __syncthreads();
    for (int i = t; i < 4096; i += 256) {
        int r = i >> 6, e = i & 63;
        outp[(size_t)(p0 + r) * 64 + e] = tile[e][r];
    }
}

// ---------------- Kernel F (fallback): out = A_big * vT via MFMA (no LDS) ----------------
__global__ __launch_bounds__(256) void k_out(const u16* __restrict__ Abig,
                                             const u16* __restrict__ vT,
                                             float* __restrict__ outb) {
    const int p0 = blockIdx.x << 6;
    const int t = threadIdx.x, lane = t & 63, w = t >> 6;
    const int l15 = lane & 15, l4 = lane >> 4;

    bf16x8 Af[2][4];
#pragma unroll
    for (int cf = 0; cf < 2; ++cf)
#pragma unroll
        for (int ks = 0; ks < 4; ++ks)
            Af[cf][ks] = *(const bf16x8*)&Abig[(size_t)(32 * w + 16 * cf + l15) * 128 + 32 * ks + 8 * l4];

    f32x4 zz = {0.f, 0.f, 0.f, 0.f};
    f32x4 acc[2][4];
#pragma unroll
    for (int cf = 0; cf < 2; ++cf)
#pragma unroll
        for (int nf = 0; nf < 4; ++nf) acc[cf][nf] = zz;

#pragma unroll
    for (int ks = 0; ks < 4; ++ks) {
        bf16x8 Bf[4];
#pragma unroll
        for (int nf = 0; nf < 4; ++nf)
            Bf[nf] = *(const bf16x8*)&vT[(size_t)(p0 + 16 * nf + l15) * 128 + 32 * ks + 8 * l4];
#pragma unroll
        for (int cf = 0; cf < 2; ++cf)
#pragma unroll
            for (int nf = 0; nf < 4; ++nf)
                acc[cf][nf] = __builtin_amdgcn_mfma_f32_16x16x32_bf16(Af[cf][ks], Bf[nf], acc[cf][nf], 0, 0, 0);
    }

    float2* o2 = (float2*)outb;
#pragma unroll
    for (int cf = 0; cf < 2; ++cf)
#pragma unroll
        for (int nf = 0; nf < 4; ++nf) {
            int co = 16 * w + 8 * cf + 2 * l4;
            int p = p0 + 16 * nf + l15;
            o2[(size_t)co * HWS + p]       = make_float2(acc[cf][nf][0], acc[cf][nf][1]);
            o2[(size_t)(co + 1) * HWS + p] = make_float2(acc[cf][nf][2], acc[cf][nf][3]);
        }
}

// ---------------- Kernel F2 (fused): out = A_big * v via LDS-staged vpack ----------------
__global__ __launch_bounds__(256) void k_out2(const u16* __restrict__ Abig,
                                              const u32* __restrict__ vpk,
                                              float* __restrict__ outb) {
    __shared__ u32 Tep[64][65];
    const int p0 = blockIdx.x << 6;
    const int t = threadIdx.x, lane = t & 63, w = t >> 6;
    const int l15 = lane & 15, l4 = lane >> 4;

    bf16x8 Af[2][4];
#pragma unroll
    for (int cf = 0; cf < 2; ++cf)
#pragma unroll
        for (int ks = 0; ks < 4; ++ks)
            Af[cf][ks] = *(const bf16x8*)&Abig[(size_t)(32 * w + 16 * cf + l15) * 128 + 32 * ks + 8 * l4];

    for (int i = t; i < 4096; i += 256) {
        int e = i >> 6, tok = i & 63;
        Tep[e][tok] = vpk[(size_t)e * HWS + p0 + tok];
    }
    __syncthreads();

    f32x4 zz = {0.f, 0.f, 0.f, 0.f};
    f32x4 acc[2][4];
#pragma unroll
    for (int cf = 0; cf < 2; ++cf)
#pragma unroll
        for (int nf = 0; nf < 4; ++nf) acc[cf][nf] = zz;

#pragma unroll
    for (int ks = 0; ks < 4; ++ks) {
        bf16x8 Bf[4];
#pragma unroll
        for (int nf = 0; nf < 4; ++nf) {
            int tok = 16 * nf + l15;
            int e0 = 16 * ks + 4 * l4;
            union { u32 u[4]; bf16x8 v; } bb;
#pragma unroll
            for (int j = 0; j < 4; ++j) bb.u[j] = Tep[e0 + j][tok];
            Bf[nf] = bb.v;
        }
#pragma unroll
        for (int cf = 0; cf < 2; ++cf)
#pragma unroll
            for (int nf = 0; nf < 4; ++nf)
                acc[cf][nf] = __builtin_amdgcn_mfma_f32_16x16x32_bf16(Af[cf][ks], Bf[nf], acc[cf][nf], 0, 0, 0);
    }

    float2* o2 = (float2*)outb;
#pragma unroll
    for (int cf = 0; cf < 2; ++cf)
#pragma unroll
        for (int nf = 0; nf < 4; ++nf) {
            int co = 16 * w + 8 * cf + 2 * l4;
            int p = p0 + 16 * nf + l15;
            o2[(size_t)co * HWS + p]       = make_float2(acc[cf][nf][0], acc[cf][nf][1]);
            o2[(size_t)(co + 1) * HWS + p] = make_float2(acc[cf][nf][2], acc[cf][nf][3]);
        }
}

extern "C" void kernel_launch(void* const* d_in, const int* in_sizes, int n_in,
                              void* d_out, int out_size, void* d_ws, size_t ws_size,
                              hipStream_t stream) {
    const float* x      = (const float*)d_in[0];
    const float* qkv_wr = (const float*)d_in[1];
    const float* qkv_wi = (const float*)d_in[2];
    const float* dw_wr  = (const float*)d_in[3];
    const float* dw_wi  = (const float*)d_in[4];
    const float* p_wr   = (const float*)d_in[5];
    const float* p_wi   = (const float*)d_in[6];
    float* out = (float*)d_out;

    const bool fused = (ws_size >= 118200000ull);   // room for separate vpack buffer

    char* base = (char*)d_ws;
    u32*   qs_u = (u32*)base;                               // 50,724,864 B
    u16*   dwp  = (u16*)(base + 50724864);                  // 33,554,432 B
    char*  xreg = base + 50724864 + 33554432;               // 16,777,216 B (xT; vT in fallback)
    u16*   xTr  = (u16*)xreg;
    u16*   xTi  = xTr + (size_t)HWS * 64;
    u32*   vT   = (u32*)xreg;                               // fallback: vT aliases xT (dead)
    u32*   vpkW = (u32*)(base + 101056512);                 // fused path only: 16,777,216 B
    size_t tail = fused ? 117833728ull : 101056512ull;
    u16*   wbf  = (u16*)(base + tail);                      // 73,728 B
    float* rnsum = (float*)(base + tail + 73728);
    float* attn  = rnsum + 512;
    float* Pbuf  = attn + 16384;
    u16*   Abig  = (u16*)(Pbuf + 16384);

    k_wcvt<<<48, 256, 0, stream>>>(qkv_wr, qkv_wi, wbf);
    k_zero<<<66, 256, 0, stream>>>(rnsum, 512 + 16384);

    for (int b = 0; b < 2; ++b) {
        const float* xb = x + (size_t)b * 64 * HWS * 2;
        u32* vpack = fused ? vpkW : (u32*)(out + (size_t)b * 64 * HWS * 2);
        k_xt<<<1024, 256, 0, stream>>>(xb, xTr, xTi);
        k_qkv<<<dim3(6, 258), 256, 0, stream>>>(xTr, xTi, wbf, qs_u);
        k_dw<<<192 * HWS / 4 / 256, 256, 0, stream>>>(qs_u, dw_wr, dw_wi, dwp, vpack);
        k_qk<<<dim3(64, 2), 256, 0, stream>>>(dwp, rnsum, attn, b, HWS);
        k_prob<<<2, 64, 0, stream>>>(attn, rnsum, Pbuf, b);
        k_M<<<16, 256, 0, stream>>>(Pbuf, p_wr, p_wi, Abig, b);
        if (fused) {
            k_out2<<<1024, 256, 0, stream>>>(Abig + (size_t)b * 16384, vpkW,
                                             out + (size_t)b * 64 * HWS * 2);
        }
    }
    if (!fused) {
        for (int b = 0; b < 2; ++b) {
            u32* vpack = (u32*)(out + (size_t)b * 64 * HWS * 2);
            k_vt<<<1024, 256, 0, stream>>>(vpack, vT);
            k_out<<<1024, 256, 0, stream>>>(Abig + (size_t)b * 16384, (const u16*)vT,
                                            out + (size_t)b * 64 * HWS * 2);
        }
    }
}

// Round 15
// 207.739 us; speedup vs baseline: 2.3251x; 1.1815x over previous
//
#include <hip/hip_runtime.h>

#define HWS 65536   // 256*256
#define SPZ 66048   // (256+2)*256 halo strip positions

typedef __attribute__((ext_vector_type(8))) short bf16x8;
typedef __attribute__((ext_vector_type(4))) float f32x4;
typedef unsigned int u32;
typedef unsigned short u16;

__device__ __forceinline__ u16 f2bf(float x) {
    u32 u = __float_as_uint(x);
    return (u16)((u + 0x7fffu + ((u >> 16) & 1u)) >> 16);
}
__device__ __forceinline__ float bf2f(u32 h) { return __uint_as_float(h << 16); }
__device__ __forceinline__ u32 pack2(float a, float b) {
    return (u32)f2bf(a) | ((u32)f2bf(b) << 16);
}

// ---------------- prep: weight cvt + zero accumulators (one launch) ----------------
__global__ void k_prep(const float* __restrict__ wr, const float* __restrict__ wi,
                       u16* __restrict__ wbf, float* __restrict__ zbuf, int nz) {
    int i = blockIdx.x * 256 + threadIdx.x;
    if (i < 12288) {
        wbf[i]         = f2bf(wr[i]);
        wbf[12288 + i] = f2bf(wi[i]);
        wbf[24576 + i] = f2bf(-wi[i]);
    }
    if (i < nz) zbuf[i] = 0.f;
}

// ---------------- Kernel X: transpose+convert x -> xTr/xTi bf16 [HWS][64] ----------------
__global__ __launch_bounds__(256) void k_xt(const float* __restrict__ x,
                                            u16* __restrict__ xTr,
                                            u16* __restrict__ xTi,
                                            size_t xs, size_t ts) {
    const int b = blockIdx.z;
    x += (size_t)b * xs; xTr += (size_t)b * ts; xTi += (size_t)b * ts;
    __shared__ u16 Tr[64][73], Ti[64][73];
    int p0 = blockIdx.x << 6;
    int t = threadIdx.x;
    const float2* x2 = (const float2*)x;
    for (int i = t; i < 4096; i += 256) {
        int ci = i >> 6, c = i & 63;
        float2 v = x2[(size_t)ci * HWS + p0 + c];
        Tr[c][ci] = f2bf(v.x);
        Ti[c][ci] = f2bf(v.y);
    }
    __syncthreads();
    for (int i = t; i < 4096; i += 256) {
        int rr = i >> 6, ci = i & 63;
        xTr[(size_t)(p0 + rr) * 64 + ci] = Tr[rr][ci];
        xTi[(size_t)(p0 + rr) * 64 + ci] = Ti[rr][ci];
    }
}

// ---------------- Kernel A: qkv 1x1 complex conv, global->MFMA, no LDS ----------------
__global__ __launch_bounds__(256) void k_qkv(const u16* __restrict__ xTr,
                                             const u16* __restrict__ xTi,
                                             const u16* __restrict__ wbf,
                                             u32* __restrict__ qs,
                                             size_t ts, size_t qsst) {
    const int b = blockIdx.z;
    xTr += (size_t)b * ts; xTi += (size_t)b * ts; qs += (size_t)b * qsst;
    const int cog = blockIdx.x;          // 0..5, 32 co each
    const int rt  = blockIdx.y;          // 0..257
    const int w   = rt - 1;              // image row (may be OOB -> zeros)
    const int t = threadIdx.x, lane = t & 63, wv = t >> 6;
    const int l15 = lane & 15, l4 = lane >> 4;
    const bool valid = (unsigned)w < 256u;

    bf16x8 Ar[2][2], Ai[2][2], An[2][2];
#pragma unroll
    for (int cf = 0; cf < 2; ++cf)
#pragma unroll
        for (int ks = 0; ks < 2; ++ks) {
            size_t off = (size_t)(cog * 32 + 16 * cf + l15) * 64 + 32 * ks + 8 * l4;
            Ar[cf][ks] = *(const bf16x8*)&wbf[off];
            Ai[cf][ks] = *(const bf16x8*)&wbf[12288 + off];
            An[cf][ks] = *(const bf16x8*)&wbf[24576 + off];
        }

    const f32x4 zz = {0.f, 0.f, 0.f, 0.f};
#pragma unroll
    for (int pf = 0; pf < 4; ++pf) {
        f32x4 cr[2] = {zz, zz}, cim[2] = {zz, zz};
        if (valid) {
            bf16x8 br[2], bi[2];
#pragma unroll
            for (int ks = 0; ks < 2; ++ks) {
                size_t boff = (size_t)(w * 256 + wv * 64 + pf * 16 + l15) * 64
                              + 32 * ks + 8 * l4;
                br[ks] = *(const bf16x8*)&xTr[boff];
                bi[ks] = *(const bf16x8*)&xTi[boff];
            }
#pragma unroll
            for (int ks = 0; ks < 2; ++ks)
#pragma unroll
                for (int cf = 0; cf < 2; ++cf) {
                    cr[cf]  = __builtin_amdgcn_mfma_f32_16x16x32_bf16(Ar[cf][ks], br[ks], cr[cf], 0, 0, 0);
                    cr[cf]  = __builtin_amdgcn_mfma_f32_16x16x32_bf16(An[cf][ks], bi[ks], cr[cf], 0, 0, 0);
                    cim[cf] = __builtin_amdgcn_mfma_f32_16x16x32_bf16(Ai[cf][ks], br[ks], cim[cf], 0, 0, 0);
                    cim[cf] = __builtin_amdgcn_mfma_f32_16x16x32_bf16(Ar[cf][ks], bi[ks], cim[cf], 0, 0, 0);
                }
        }
        int p = rt * 256 + wv * 64 + pf * 16 + l15;
#pragma unroll
        for (int cf = 0; cf < 2; ++cf)
#pragma unroll
            for (int r = 0; r < 4; ++r) {
                int co = cog * 32 + 16 * cf + 4 * l4 + r;
                qs[(size_t)co * SPZ + p] = valid ? pack2(cr[cf][r], cim[cf][r]) : 0u;
            }
    }
}

// ---------------- Kernel B: depthwise 3x3 complex conv, 4 pixels/thread ----------------
__global__ __launch_bounds__(256) void k_dw(const u32* __restrict__ qs,
                                            const float* __restrict__ wr,
                                            const float* __restrict__ wi,
                                            u16* __restrict__ dwp,
                                            u32* __restrict__ vpack,
                                            size_t qsst, size_t dst, size_t vst) {
    const int b = blockIdx.z;
    qs += (size_t)b * qsst; dwp += (size_t)b * dst; vpack += (size_t)b * vst;
    int idx = blockIdx.x * 256 + threadIdx.x;   // over 192*HWS/4
    int p4 = (idx & (HWS / 4 - 1)) << 2;        // 4 consecutive h
    int ch = idx >> 14;
    int r = p4 >> 8, h = p4 & 255;
    const u32* src = qs + (size_t)ch * SPZ + r * 256;

    float wrl[9], wil[9];
#pragma unroll
    for (int tt = 0; tt < 9; ++tt) { wrl[tt] = wr[ch * 9 + tt]; wil[tt] = wi[ch * 9 + tt]; }

    u32 uv[3][6];
#pragma unroll
    for (int du = 0; du < 3; ++du)
#pragma unroll
        for (int j = 0; j < 6; ++j) {
            int hh = h - 1 + j;
            uv[du][j] = ((unsigned)hh < 256u) ? src[du * 256 + hh] : 0u;
        }
    float vr[3][6], vi[3][6];
#pragma unroll
    for (int du = 0; du < 3; ++du)
#pragma unroll
        for (int j = 0; j < 6; ++j) {
            vr[du][j] = bf2f(uv[du][j] & 0xffffu);
            vi[du][j] = bf2f(uv[du][j] >> 16);
        }

    float ar[4] = {0.f, 0.f, 0.f, 0.f}, ai[4] = {0.f, 0.f, 0.f, 0.f};
#pragma unroll
    for (int du = 0; du < 3; ++du)
#pragma unroll
        for (int ct = 0; ct < 3; ++ct) {
            float w0 = wrl[du * 3 + ct], w1 = wil[du * 3 + ct];
#pragma unroll
            for (int px = 0; px < 4; ++px) {
                float xr = vr[du][px + ct], xi = vi[du][px + ct];
                ar[px] = fmaf(w0, xr, ar[px]); ar[px] = fmaf(-w1, xi, ar[px]);
                ai[px] = fmaf(w1, xr, ai[px]); ai[px] = fmaf(w0, xi, ai[px]);
            }
        }

    if (ch < 128) {
        int pl = (ch < 64) ? 0 : 2;
        int c2 = ch & 63;
        uint2 rw = make_uint2(pack2(ar[0], ar[1]), pack2(ar[2], ar[3]));
        uint2 iw = make_uint2(pack2(ai[0], ai[1]), pack2(ai[2], ai[3]));
        *(uint2*)&dwp[(size_t)(pl * 64 + c2) * HWS + p4] = rw;
        *(uint2*)&dwp[(size_t)((pl + 1) * 64 + c2) * HWS + p4] = iw;
    } else {
        int e = ch - 128;
        uint4 vv = make_uint4(pack2(ar[0], ai[0]), pack2(ar[1], ai[1]),
                              pack2(ar[2], ai[2]), pack2(ar[3], ai[3]));
        *(uint4*)&vpack[(size_t)e * HWS + p4] = vv;
    }
}

// ---------------- Kernel C: q k^T + fused sumsq via MFMA (no LDS) ----------------
// grid (64 chunks, 2 d, nb)
__global__ __launch_bounds__(256) void k_qk(const u16* __restrict__ dwp,
                                            float* __restrict__ rnsum,
                                            float* __restrict__ attn,
                                            int b0, size_t dst) {
    const int z = blockIdx.z;
    const int b = b0 + z;
    dwp += (size_t)z * dst;
    const int chunk = blockIdx.x;        // 0..63
    const int d = blockIdx.y;
    const int Kc = HWS >> 6;
    const int kc0 = chunk * Kc;
    const u16* qp = dwp + (size_t)d * 64 * HWS;
    const u16* kp = dwp + (size_t)(2 + d) * 64 * HWS;

    const int t = threadIdx.x, lane = t & 63, wid = t >> 6;
    const int wy = wid >> 1, wx = wid & 1;
    const int l15 = lane & 15, l4 = lane >> 4;

    f32x4 zz = {0.f, 0.f, 0.f, 0.f};
    f32x4 acc[2][2] = {{zz, zz}, {zz, zz}};
    float sq[2] = {0.f, 0.f}, sk[2] = {0.f, 0.f};

    const int iters = Kc >> 5;
    for (int ks = 0; ks < iters; ++ks) {
        int k0 = kc0 + ks * 32 + 8 * l4;
        bf16x8 aq[2], bk[2];
#pragma unroll
        for (int cf = 0; cf < 2; ++cf)
            aq[cf] = *(const bf16x8*)&qp[(size_t)(32 * wy + 16 * cf + l15) * HWS + k0];
#pragma unroll
        for (int ef = 0; ef < 2; ++ef)
            bk[ef] = *(const bf16x8*)&kp[(size_t)(32 * wx + 16 * ef + l15) * HWS + k0];

        if (wx == 0)
#pragma unroll
            for (int cf = 0; cf < 2; ++cf)
#pragma unroll
                for (int j = 0; j < 8; ++j) {
                    float f = bf2f((u16)aq[cf][j]);
                    sq[cf] = fmaf(f, f, sq[cf]);
                }
        if (wy == 0)
#pragma unroll
            for (int ef = 0; ef < 2; ++ef)
#pragma unroll
                for (int j = 0; j < 8; ++j) {
                    float f = bf2f((u16)bk[ef][j]);
                    sk[ef] = fmaf(f, f, sk[ef]);
                }

#pragma unroll
        for (int cf = 0; cf < 2; ++cf)
#pragma unroll
            for (int ef = 0; ef < 2; ++ef)
                acc[cf][ef] = __builtin_amdgcn_mfma_f32_16x16x32_bf16(aq[cf], bk[ef], acc[cf][ef], 0, 0, 0);
    }

#pragma unroll
    for (int cf = 0; cf < 2; ++cf)
#pragma unroll
        for (int ef = 0; ef < 2; ++ef)
#pragma unroll
            for (int r = 0; r < 4; ++r) {
                int cq = 32 * wy + 16 * cf + 4 * l4 + r;
                int ce = 32 * wx + 16 * ef + l15;
                atomicAdd(&attn[((b * 2 + d) * 64 + cq) * 64 + ce], acc[cf][ef][r]);
            }

    if (wx == 0)
#pragma unroll
        for (int cf = 0; cf < 2; ++cf) {
            float v = sq[cf];
            v += __shfl_xor(v, 16);
            v += __shfl_xor(v, 32);
            if (lane < 16)
                atomicAdd(&rnsum[((size_t)b * 128 + 32 * wy + 16 * cf + lane) * 2 + d], v);
        }
    if (wy == 0)
#pragma unroll
        for (int ef = 0; ef < 2; ++ef) {
            float v = sk[ef];
            v += __shfl_xor(v, 16);
            v += __shfl_xor(v, 32);
            if (lane < 16)
                atomicAdd(&rnsum[((size_t)b * 128 + 64 + 32 * wx + 16 * ef + lane) * 2 + d], v);
        }
}

// ---------------- Kernel D1: scale + row softmax -> P (grid (2 d, nb), 64 thr) ----------------
__global__ __launch_bounds__(64) void k_prob(const float* __restrict__ attn,
                                             const float* __restrict__ rnsum,
                                             float* __restrict__ P, int b0) {
    int d = blockIdx.x;
    int b = b0 + blockIdx.y;
    int t = threadIdx.x;
    __shared__ float rks[64];
    float sk = rnsum[((size_t)b * 128 + 64 + t) * 2 + d];
    rks[t] = 1.0f / fmaxf(sqrtf(sk), 1e-12f);
    float sq = rnsum[((size_t)b * 128 + t) * 2 + d];
    float rq = 1.0f / fmaxf(sqrtf(sq), 1e-12f);
    __syncthreads();

    const float* arow = attn + ((size_t)(b * 2 + d) * 64 + t) * 64;
    float v[64];
    float m = -1e30f;
#pragma unroll
    for (int e = 0; e < 64; ++e) { v[e] = arow[e] * rq * rks[e]; m = fmaxf(m, v[e]); }
    float ssum = 0.f;
#pragma unroll
    for (int e = 0; e < 64; ++e) { v[e] = __expf(v[e] - m); ssum += v[e]; }
    float r = 1.0f / ssum;
    float* prow = P + ((size_t)(b * 2 + d) * 64 + t) * 64;
#pragma unroll
    for (int e = 0; e < 64; ++e) prow[e] = v[e] * r;
}

// ---------------- Kernel D2: build A_big from P and proj weights (grid (16, nb)) ----------------
__global__ __launch_bounds__(256) void k_M(const float* __restrict__ P,
                                           const float* __restrict__ pwr,
                                           const float* __restrict__ pwi,
                                           u16* __restrict__ Abig, int b0) {
    int b = b0 + blockIdx.y;
    int pair = blockIdx.x * 256 + threadIdx.x;   // 0..4095
    __shared__ float P0[64][64], P1[64][64];
    __shared__ float Wr[64][64], Wi2[64][64];
    for (int i = threadIdx.x; i < 4096; i += 256) {
        P0[i >> 6][i & 63] = P[(size_t)(b * 2 + 0) * 4096 + i];
        P1[i >> 6][i & 63] = P[(size_t)(b * 2 + 1) * 4096 + i];
        Wr[i >> 6][i & 63] = pwr[i];
        Wi2[i >> 6][i & 63] = pwi[i];
    }
    __syncthreads();
    int co = pair >> 6, e = pair & 63;
    float m1 = 0.f, m2 = 0.f, m3 = 0.f, m4 = 0.f;
#pragma unroll 8
    for (int c = 0; c < 64; ++c) {
        float pr = Wr[co][c], pi = Wi2[co][c];
        float a0 = P0[c][e], a1 = P1[c][e];
        m1 = fmaf(pr, a0, m1);
        m2 = fmaf(pi, a1, m2);
        m3 = fmaf(pr, a1, m3);
        m4 = fmaf(pi, a0, m4);
    }
    u16* AB = Abig + (size_t)b * 16384;
    AB[(2 * co) * 128 + 2 * e]         = f2bf(m1);
    AB[(2 * co) * 128 + 2 * e + 1]     = f2bf(-m2);
    AB[(2 * co + 1) * 128 + 2 * e]     = f2bf(m4);
    AB[(2 * co + 1) * 128 + 2 * e + 1] = f2bf(m3);
}

// ---------------- Kernel E (fallback): transpose vpack [64][HWS] u32 -> vT [HWS][64] u32 ----------------
__global__ __launch_bounds__(256) void k_vt(const u32* __restrict__ in,
                                            u32* __restrict__ outp) {
    __shared__ u32 tile[64][65];
    int p0 = blockIdx.x << 6;
    int t = threadIdx.x;
    for (int i = t; i < 4096; i += 256) {
        int e = i >> 6, c = i & 63;
        tile[e][c] = in[(size_t)e * HWS + p0 + c];
    }
    __syncthreads();
    for (int i = t; i < 4096; i += 256) {
        int r = i >> 6, e = i & 63;
        outp[(size_t)(p0 + r) * 64 + e] = tile[e][r];
    }
}

// ---------------- Kernel F (fallback): out = A_big * vT via MFMA (no LDS) ----------------
__global__ __launch_bounds__(256) void k_out(const u16* __restrict__ Abig,
                                             const u16* __restrict__ vT,
                                             float* __restrict__ outb) {
    const int p0 = blockIdx.x << 6;
    const int t = threadIdx.x, lane = t & 63, w = t >> 6;
    const int l15 = lane & 15, l4 = lane >> 4;

    bf16x8 Af[2][4];
#pragma unroll
    for (int cf = 0; cf < 2; ++cf)
#pragma unroll
        for (int ks = 0; ks < 4; ++ks)
            Af[cf][ks] = *(const bf16x8*)&Abig[(size_t)(32 * w + 16 * cf + l15) * 128 + 32 * ks + 8 * l4];

    f32x4 zz = {0.f, 0.f, 0.f, 0.f};
    f32x4 acc[2][4];
#pragma unroll
    for (int cf = 0; cf < 2; ++cf)
#pragma unroll
        for (int nf = 0; nf < 4; ++nf) acc[cf][nf] = zz;

#pragma unroll
    for (int ks = 0; ks < 4; ++ks) {
        bf16x8 Bf[4];
#pragma unroll
        for (int nf = 0; nf < 4; ++nf)
            Bf[nf] = *(const bf16x8*)&vT[(size_t)(p0 + 16 * nf + l15) * 128 + 32 * ks + 8 * l4];
#pragma unroll
        for (int cf = 0; cf < 2; ++cf)
#pragma unroll
            for (int nf = 0; nf < 4; ++nf)
                acc[cf][nf] = __builtin_amdgcn_mfma_f32_16x16x32_bf16(Af[cf][ks], Bf[nf], acc[cf][nf], 0, 0, 0);
    }

    float2* o2 = (float2*)outb;
#pragma unroll
    for (int cf = 0; cf < 2; ++cf)
#pragma unroll
        for (int nf = 0; nf < 4; ++nf) {
            int co = 16 * w + 8 * cf + 2 * l4;
            int p = p0 + 16 * nf + l15;
            o2[(size_t)co * HWS + p]       = make_float2(acc[cf][nf][0], acc[cf][nf][1]);
            o2[(size_t)(co + 1) * HWS + p] = make_float2(acc[cf][nf][2], acc[cf][nf][3]);
        }
}

// ---------------- Kernel F2: out = A_big * v via LDS-staged vpack ----------------
__global__ __launch_bounds__(256) void k_out2(const u16* __restrict__ Abig,
                                              const u32* __restrict__ vpk,
                                              float* __restrict__ outb,
                                              int b0, size_t vst, size_t ost) {
    const int z = blockIdx.z;
    const int b = b0 + z;
    vpk += (size_t)z * vst; outb += (size_t)z * ost;
    __shared__ u32 Tep[64][65];
    const int p0 = blockIdx.x << 6;
    const int t = threadIdx.x, lane = t & 63, w = t >> 6;
    const int l15 = lane & 15, l4 = lane >> 4;
    const u16* AB = Abig + (size_t)b * 16384;

    bf16x8 Af[2][4];
#pragma unroll
    for (int cf = 0; cf < 2; ++cf)
#pragma unroll
        for (int ks = 0; ks < 4; ++ks)
            Af[cf][ks] = *(const bf16x8*)&AB[(size_t)(32 * w + 16 * cf + l15) * 128 + 32 * ks + 8 * l4];

    for (int i = t; i < 4096; i += 256) {
        int e = i >> 6, tok = i & 63;
        Tep[e][tok] = vpk[(size_t)e * HWS + p0 + tok];
    }
    __syncthreads();

    f32x4 zz = {0.f, 0.f, 0.f, 0.f};
    f32x4 acc[2][4];
#pragma unroll
    for (int cf = 0; cf < 2; ++cf)
#pragma unroll
        for (int nf = 0; nf < 4; ++nf) acc[cf][nf] = zz;

#pragma unroll
    for (int ks = 0; ks < 4; ++ks) {
        bf16x8 Bf[4];
#pragma unroll
        for (int nf = 0; nf < 4; ++nf) {
            int tok = 16 * nf + l15;
            int e0 = 16 * ks + 4 * l4;
            union { u32 u[4]; bf16x8 v; } bb;
#pragma unroll
            for (int j = 0; j < 4; ++j) bb.u[j] = Tep[e0 + j][tok];
            Bf[nf] = bb.v;
        }
#pragma unroll
        for (int cf = 0; cf < 2; ++cf)
#pragma unroll
            for (int nf = 0; nf < 4; ++nf)
                acc[cf][nf] = __builtin_amdgcn_mfma_f32_16x16x32_bf16(Af[cf][ks], Bf[nf], acc[cf][nf], 0, 0, 0);
    }

    float2* o2 = (float2*)outb;
#pragma unroll
    for (int cf = 0; cf < 2; ++cf)
#pragma unroll
        for (int nf = 0; nf < 4; ++nf) {
            int co = 16 * w + 8 * cf + 2 * l4;
            int p = p0 + 16 * nf + l15;
            o2[(size_t)co * HWS + p]       = make_float2(acc[cf][nf][0], acc[cf][nf][1]);
            o2[(size_t)(co + 1) * HWS + p] = make_float2(acc[cf][nf][2], acc[cf][nf][3]);
        }
}

extern "C" void kernel_launch(void* const* d_in, const int* in_sizes, int n_in,
                              void* d_out, int out_size, void* d_ws, size_t ws_size,
                              hipStream_t stream) {
    const float* x      = (const float*)d_in[0];
    const float* qkv_wr = (const float*)d_in[1];
    const float* qkv_wi = (const float*)d_in[2];
    const float* dw_wr  = (const float*)d_in[3];
    const float* dw_wi  = (const float*)d_in[4];
    const float* p_wr   = (const float*)d_in[5];
    const float* p_wi   = (const float*)d_in[6];
    float* out = (float*)d_out;
    const size_t OSTR = (size_t)64 * HWS * 2;   // floats per batch of output

    const bool z2  = ws_size >= 236000000ull;   // fully per-b-strided buffers
    const bool f14 = !z2 && ws_size >= 118200000ull;

    char* base = (char*)d_ws;

    if (z2) {
        // per-b strided layout (~235.9 MB)
        u32*   qs   = (u32*)base;                          // 2 x 50,724,864 B
        u16*   dwp  = (u16*)(base + 101449728);            // 2 x 33,554,432 B
        u16*   xTr  = (u16*)(base + 168558592);            // 2 x (8.39+8.39) MB
        u16*   xTi  = xTr + (size_t)HWS * 64;
        u32*   vpk  = (u32*)(base + 202113024);            // 2 x 16,777,216 B
        u16*   wbf  = (u16*)(base + 235667456);
        float* rnsum = (float*)(base + 235741184);
        float* attn  = rnsum + 512;
        float* Pbuf  = attn + 16384;
        u16*   Abig  = (u16*)(Pbuf + 16384);

        const size_t XT_ST = 8388608;     // u16 per b (both planes)
        const size_t QS_ST = 12681216;    // u32 per b
        const size_t DW_ST = 16777216;    // u16 per b
        const size_t VP_ST = 4194304;     // u32 per b

        k_prep<<<66, 256, 0, stream>>>(qkv_wr, qkv_wi, wbf, rnsum, 512 + 16384);
        k_xt<<<dim3(1024, 1, 2), 256, 0, stream>>>(x, xTr, xTi, OSTR, XT_ST);
        k_qkv<<<dim3(6, 258, 2), 256, 0, stream>>>(xTr, xTi, wbf, qs, XT_ST, QS_ST);
        k_dw<<<dim3(12288, 1, 2), 256, 0, stream>>>(qs, dw_wr, dw_wi, dwp, vpk,
                                                    QS_ST, DW_ST, VP_ST);
        k_qk<<<dim3(64, 2, 2), 256, 0, stream>>>(dwp, rnsum, attn, 0, DW_ST);
        k_prob<<<dim3(2, 2), 64, 0, stream>>>(attn, rnsum, Pbuf, 0);
        k_M<<<dim3(16, 2), 256, 0, stream>>>(Pbuf, p_wr, p_wi, Abig, 0);
        k_out2<<<dim3(1024, 1, 2), 256, 0, stream>>>(Abig, vpk, out, 0, VP_ST, OSTR);
        return;
    }

    // shared-buffer layouts (round-14 / round-13 proven paths)
    u32*   qs   = (u32*)base;                               // 50,724,864 B
    u16*   dwp  = (u16*)(base + 50724864);                  // 33,554,432 B
    char*  xreg = base + 50724864 + 33554432;               // 16,777,216 B
    u16*   xTr  = (u16*)xreg;
    u16*   xTi  = xTr + (size_t)HWS * 64;
    u32*   vT   = (u32*)xreg;                               // fallback-13: vT aliases xT
    u32*   vpkW = (u32*)(base + 101056512);                 // f14 only
    size_t tail = f14 ? 117833728ull : 101056512ull;
    u16*   wbf  = (u16*)(base + tail);
    float* rnsum = (float*)(base + tail + 73728);
    float* attn  = rnsum + 512;
    float* Pbuf  = attn + 16384;
    u16*   Abig  = (u16*)(Pbuf + 16384);

    k_prep<<<66, 256, 0, stream>>>(qkv_wr, qkv_wi, wbf, rnsum, 512 + 16384);

    for (int b = 0; b < 2; ++b) {
        const float* xb = x + (size_t)b * OSTR;
        u32* vpack = f14 ? vpkW : (u32*)(out + (size_t)b * OSTR);
        k_xt<<<dim3(1024, 1, 1), 256, 0, stream>>>(xb, xTr, xTi, 0, 0);
        k_qkv<<<dim3(6, 258, 1), 256, 0, stream>>>(xTr, xTi, wbf, qs, 0, 0);
        k_dw<<<dim3(12288, 1, 1), 256, 0, stream>>>(qs, dw_wr, dw_wi, dwp, vpack, 0, 0, 0);
        k_qk<<<dim3(64, 2, 1), 256, 0, stream>>>(dwp, rnsum, attn, b, 0);
        k_prob<<<dim3(2, 1), 64, 0, stream>>>(attn, rnsum, Pbuf, b);
        k_M<<<dim3(16, 1), 256, 0, stream>>>(Pbuf, p_wr, p_wi, Abig, b);
        if (f14)
            k_out2<<<dim3(1024, 1, 1), 256, 0, stream>>>(Abig, vpkW,
                                                         out + (size_t)b * OSTR, b, 0, 0);
    }
    if (!f14) {
        for (int b = 0; b < 2; ++b) {
            u32* vpack = (u32*)(out + (size_t)b * OSTR);
            k_vt<<<1024, 256, 0, stream>>>(vpack, vT);
            k_out<<<1024, 256, 0, stream>>>(Abig + (size_t)b * 16384, (const u16*)vT,
                                            out + (size_t)b * OSTR);
        }
    }
}

// Round 16
// 207.021 us; speedup vs baseline: 2.3332x; 1.0035x over previous
//
#include <hip/hip_runtime.h>

#define HWS 65536   // 256*256
#define SPZ 66048   // (256+2)*256 halo strip positions

typedef __attribute__((ext_vector_type(8))) short bf16x8;
typedef __attribute__((ext_vector_type(4))) float f32x4;
typedef unsigned int u32;
typedef unsigned short u16;

__device__ __forceinline__ u16 f2bf(float x) {
    u32 u = __float_as_uint(x);
    return (u16)((u + 0x7fffu + ((u >> 16) & 1u)) >> 16);
}
__device__ __forceinline__ float bf2f(u32 h) { return __uint_as_float(h << 16); }
// HW packed bf16 convert (RNE, identical rounding to f2bf): lo=a, hi=b
__device__ __forceinline__ u32 cvtpk(float a, float b) {
    u32 r;
    asm("v_cvt_pk_bf16_f32 %0, %1, %2" : "=v"(r) : "v"(a), "v"(b));
    return r;
}
__device__ __forceinline__ u32 pack2(float a, float b) {
    return (u32)f2bf(a) | ((u32)f2bf(b) << 16);
}

// ---------------- prep: weight cvt + zero accumulators (one launch) ----------------
__global__ void k_prep(const float* __restrict__ wr, const float* __restrict__ wi,
                       u16* __restrict__ wbf, float* __restrict__ zbuf, int nz) {
    int i = blockIdx.x * 256 + threadIdx.x;
    if (i < 12288) {
        wbf[i]         = f2bf(wr[i]);
        wbf[12288 + i] = f2bf(wi[i]);
        wbf[24576 + i] = f2bf(-wi[i]);
    }
    if (i < nz) zbuf[i] = 0.f;
}

// ---------------- Kernel X: transpose+convert x -> xTr/xTi bf16 [HWS][64] ----------------
// cvt_pk pairs along ci; u32-granular LDS + global stores.
__global__ __launch_bounds__(256) void k_xt(const float* __restrict__ x,
                                            u16* __restrict__ xTr,
                                            u16* __restrict__ xTi,
                                            size_t xs, size_t ts) {
    const int b = blockIdx.z;
    x += (size_t)b * xs; xTr += (size_t)b * ts; xTi += (size_t)b * ts;
    __shared__ u16 Tr[64][74], Ti[64][74];
    int p0 = blockIdx.x << 6;
    int t = threadIdx.x;
    const float2* x2 = (const float2*)x;
    for (int i = t; i < 2048; i += 256) {        // (ci-pair, c)
        int cp = i >> 6, c = i & 63;
        int ci = cp << 1;
        float2 v0 = x2[(size_t)ci * HWS + p0 + c];
        float2 v1 = x2[(size_t)(ci + 1) * HWS + p0 + c];
        *(u32*)&Tr[c][ci] = cvtpk(v0.x, v1.x);
        *(u32*)&Ti[c][ci] = cvtpk(v0.y, v1.y);
    }
    __syncthreads();
    for (int i = t; i < 2048; i += 256) {        // (row, ci-pair)
        int rr = i >> 5, cp = i & 31;
        *(u32*)&xTr[(size_t)(p0 + rr) * 64 + 2 * cp] = *(u32*)&Tr[rr][2 * cp];
        *(u32*)&xTi[(size_t)(p0 + rr) * 64 + 2 * cp] = *(u32*)&Ti[rr][2 * cp];
    }
}

// ---------------- Kernel A: qkv 1x1 complex conv, global->MFMA, no LDS ----------------
__global__ __launch_bounds__(256) void k_qkv(const u16* __restrict__ xTr,
                                             const u16* __restrict__ xTi,
                                             const u16* __restrict__ wbf,
                                             u32* __restrict__ qs,
                                             size_t ts, size_t qsst) {
    const int b = blockIdx.z;
    xTr += (size_t)b * ts; xTi += (size_t)b * ts; qs += (size_t)b * qsst;
    const int cog = blockIdx.x;          // 0..5, 32 co each
    const int rt  = blockIdx.y;          // 0..257
    const int w   = rt - 1;              // image row (may be OOB -> zeros)
    const int t = threadIdx.x, lane = t & 63, wv = t >> 6;
    const int l15 = lane & 15, l4 = lane >> 4;
    const bool valid = (unsigned)w < 256u;

    bf16x8 Ar[2][2], Ai[2][2], An[2][2];
#pragma unroll
    for (int cf = 0; cf < 2; ++cf)
#pragma unroll
        for (int ks = 0; ks < 2; ++ks) {
            size_t off = (size_t)(cog * 32 + 16 * cf + l15) * 64 + 32 * ks + 8 * l4;
            Ar[cf][ks] = *(const bf16x8*)&wbf[off];
            Ai[cf][ks] = *(const bf16x8*)&wbf[12288 + off];
            An[cf][ks] = *(const bf16x8*)&wbf[24576 + off];
        }

    const f32x4 zz = {0.f, 0.f, 0.f, 0.f};
#pragma unroll
    for (int pf = 0; pf < 4; ++pf) {
        f32x4 cr[2] = {zz, zz}, cim[2] = {zz, zz};
        if (valid) {
            bf16x8 br[2], bi[2];
#pragma unroll
            for (int ks = 0; ks < 2; ++ks) {
                size_t boff = (size_t)(w * 256 + wv * 64 + pf * 16 + l15) * 64
                              + 32 * ks + 8 * l4;
                br[ks] = *(const bf16x8*)&xTr[boff];
                bi[ks] = *(const bf16x8*)&xTi[boff];
            }
#pragma unroll
            for (int ks = 0; ks < 2; ++ks)
#pragma unroll
                for (int cf = 0; cf < 2; ++cf) {
                    cr[cf]  = __builtin_amdgcn_mfma_f32_16x16x32_bf16(Ar[cf][ks], br[ks], cr[cf], 0, 0, 0);
                    cr[cf]  = __builtin_amdgcn_mfma_f32_16x16x32_bf16(An[cf][ks], bi[ks], cr[cf], 0, 0, 0);
                    cim[cf] = __builtin_amdgcn_mfma_f32_16x16x32_bf16(Ai[cf][ks], br[ks], cim[cf], 0, 0, 0);
                    cim[cf] = __builtin_amdgcn_mfma_f32_16x16x32_bf16(Ar[cf][ks], bi[ks], cim[cf], 0, 0, 0);
                }
        }
        int p = rt * 256 + wv * 64 + pf * 16 + l15;
#pragma unroll
        for (int cf = 0; cf < 2; ++cf)
#pragma unroll
            for (int r = 0; r < 4; ++r) {
                int co = cog * 32 + 16 * cf + 4 * l4 + r;
                qs[(size_t)co * SPZ + p] = valid ? cvtpk(cr[cf][r], cim[cf][r]) : 0u;
            }
    }
}

// ---------------- Kernel B: depthwise 3x3 complex conv, 4 pixels/thread ----------------
__global__ __launch_bounds__(256) void k_dw(const u32* __restrict__ qs,
                                            const float* __restrict__ wr,
                                            const float* __restrict__ wi,
                                            u16* __restrict__ dwp,
                                            u32* __restrict__ vpack,
                                            size_t qsst, size_t dst, size_t vst) {
    const int b = blockIdx.z;
    qs += (size_t)b * qsst; dwp += (size_t)b * dst; vpack += (size_t)b * vst;
    int idx = blockIdx.x * 256 + threadIdx.x;   // over 192*HWS/4
    int p4 = (idx & (HWS / 4 - 1)) << 2;        // 4 consecutive h
    int ch = idx >> 14;
    int r = p4 >> 8, h = p4 & 255;
    const u32* src = qs + (size_t)ch * SPZ + r * 256;

    float wrl[9], wil[9];
#pragma unroll
    for (int tt = 0; tt < 9; ++tt) { wrl[tt] = wr[ch * 9 + tt]; wil[tt] = wi[ch * 9 + tt]; }

    u32 uv[3][6];
#pragma unroll
    for (int du = 0; du < 3; ++du)
#pragma unroll
        for (int j = 0; j < 6; ++j) {
            int hh = h - 1 + j;
            uv[du][j] = ((unsigned)hh < 256u) ? src[du * 256 + hh] : 0u;
        }
    float vr[3][6], vi[3][6];
#pragma unroll
    for (int du = 0; du < 3; ++du)
#pragma unroll
        for (int j = 0; j < 6; ++j) {
            vr[du][j] = bf2f(uv[du][j] & 0xffffu);
            vi[du][j] = bf2f(uv[du][j] >> 16);
        }

    float ar[4] = {0.f, 0.f, 0.f, 0.f}, ai[4] = {0.f, 0.f, 0.f, 0.f};
#pragma unroll
    for (int du = 0; du < 3; ++du)
#pragma unroll
        for (int ct = 0; ct < 3; ++ct) {
            float w0 = wrl[du * 3 + ct], w1 = wil[du * 3 + ct];
#pragma unroll
            for (int px = 0; px < 4; ++px) {
                float xr = vr[du][px + ct], xi = vi[du][px + ct];
                ar[px] = fmaf(w0, xr, ar[px]); ar[px] = fmaf(-w1, xi, ar[px]);
                ai[px] = fmaf(w1, xr, ai[px]); ai[px] = fmaf(w0, xi, ai[px]);
            }
        }

    if (ch < 128) {
        int pl = (ch < 64) ? 0 : 2;
        int c2 = ch & 63;
        uint2 rw = make_uint2(cvtpk(ar[0], ar[1]), cvtpk(ar[2], ar[3]));
        uint2 iw = make_uint2(cvtpk(ai[0], ai[1]), cvtpk(ai[2], ai[3]));
        *(uint2*)&dwp[(size_t)(pl * 64 + c2) * HWS + p4] = rw;
        *(uint2*)&dwp[(size_t)((pl + 1) * 64 + c2) * HWS + p4] = iw;
    } else {
        int e = ch - 128;
        uint4 vv = make_uint4(cvtpk(ar[0], ai[0]), cvtpk(ar[1], ai[1]),
                              cvtpk(ar[2], ai[2]), cvtpk(ar[3], ai[3]));
        *(uint4*)&vpack[(size_t)e * HWS + p4] = vv;
    }
}

// ---------------- Kernel C: q k^T + fused sumsq via MFMA (no LDS) ----------------
// grid (64 chunks, 2 d, nb)
__global__ __launch_bounds__(256) void k_qk(const u16* __restrict__ dwp,
                                            float* __restrict__ rnsum,
                                            float* __restrict__ attn,
                                            int b0, size_t dst) {
    const int z = blockIdx.z;
    const int b = b0 + z;
    dwp += (size_t)z * dst;
    const int chunk = blockIdx.x;        // 0..63
    const int d = blockIdx.y;
    const int Kc = HWS >> 6;
    const int kc0 = chunk * Kc;
    const u16* qp = dwp + (size_t)d * 64 * HWS;
    const u16* kp = dwp + (size_t)(2 + d) * 64 * HWS;

    const int t = threadIdx.x, lane = t & 63, wid = t >> 6;
    const int wy = wid >> 1, wx = wid & 1;
    const int l15 = lane & 15, l4 = lane >> 4;

    f32x4 zz = {0.f, 0.f, 0.f, 0.f};
    f32x4 acc[2][2] = {{zz, zz}, {zz, zz}};
    float sq[2] = {0.f, 0.f}, sk[2] = {0.f, 0.f};

    const int iters = Kc >> 5;
    for (int ks = 0; ks < iters; ++ks) {
        int k0 = kc0 + ks * 32 + 8 * l4;
        bf16x8 aq[2], bk[2];
#pragma unroll
        for (int cf = 0; cf < 2; ++cf)
            aq[cf] = *(const bf16x8*)&qp[(size_t)(32 * wy + 16 * cf + l15) * HWS + k0];
#pragma unroll
        for (int ef = 0; ef < 2; ++ef)
            bk[ef] = *(const bf16x8*)&kp[(size_t)(32 * wx + 16 * ef + l15) * HWS + k0];

        if (wx == 0)
#pragma unroll
            for (int cf = 0; cf < 2; ++cf)
#pragma unroll
                for (int j = 0; j < 8; ++j) {
                    float f = bf2f((u16)aq[cf][j]);
                    sq[cf] = fmaf(f, f, sq[cf]);
                }
        if (wy == 0)
#pragma unroll
            for (int ef = 0; ef < 2; ++ef)
#pragma unroll
                for (int j = 0; j < 8; ++j) {
                    float f = bf2f((u16)bk[ef][j]);
                    sk[ef] = fmaf(f, f, sk[ef]);
                }

#pragma unroll
        for (int cf = 0; cf < 2; ++cf)
#pragma unroll
            for (int ef = 0; ef < 2; ++ef)
                acc[cf][ef] = __builtin_amdgcn_mfma_f32_16x16x32_bf16(aq[cf], bk[ef], acc[cf][ef], 0, 0, 0);
    }

#pragma unroll
    for (int cf = 0; cf < 2; ++cf)
#pragma unroll
        for (int ef = 0; ef < 2; ++ef)
#pragma unroll
            for (int r = 0; r < 4; ++r) {
                int cq = 32 * wy + 16 * cf + 4 * l4 + r;
                int ce = 32 * wx + 16 * ef + l15;
                atomicAdd(&attn[((b * 2 + d) * 64 + cq) * 64 + ce], acc[cf][ef][r]);
            }

    if (wx == 0)
#pragma unroll
        for (int cf = 0; cf < 2; ++cf) {
            float v = sq[cf];
            v += __shfl_xor(v, 16);
            v += __shfl_xor(v, 32);
            if (lane < 16)
                atomicAdd(&rnsum[((size_t)b * 128 + 32 * wy + 16 * cf + lane) * 2 + d], v);
        }
    if (wy == 0)
#pragma unroll
        for (int ef = 0; ef < 2; ++ef) {
            float v = sk[ef];
            v += __shfl_xor(v, 16);
            v += __shfl_xor(v, 32);
            if (lane < 16)
                atomicAdd(&rnsum[((size_t)b * 128 + 64 + 32 * wx + 16 * ef + lane) * 2 + d], v);
        }
}

// ---------------- Kernel D1: scale + row softmax -> P (grid (2 d, nb), 64 thr) ----------------
__global__ __launch_bounds__(64) void k_prob(const float* __restrict__ attn,
                                             const float* __restrict__ rnsum,
                                             float* __restrict__ P, int b0) {
    int d = blockIdx.x;
    int b = b0 + blockIdx.y;
    int t = threadIdx.x;
    __shared__ float rks[64];
    float sk = rnsum[((size_t)b * 128 + 64 + t) * 2 + d];
    rks[t] = 1.0f / fmaxf(sqrtf(sk), 1e-12f);
    float sq = rnsum[((size_t)b * 128 + t) * 2 + d];
    float rq = 1.0f / fmaxf(sqrtf(sq), 1e-12f);
    __syncthreads();

    const float* arow = attn + ((size_t)(b * 2 + d) * 64 + t) * 64;
    float v[64];
    float m = -1e30f;
#pragma unroll
    for (int e = 0; e < 64; ++e) { v[e] = arow[e] * rq * rks[e]; m = fmaxf(m, v[e]); }
    float ssum = 0.f;
#pragma unroll
    for (int e = 0; e < 64; ++e) { v[e] = __expf(v[e] - m); ssum += v[e]; }
    float r = 1.0f / ssum;
    float* prow = P + ((size_t)(b * 2 + d) * 64 + t) * 64;
#pragma unroll
    for (int e = 0; e < 64; ++e) prow[e] = v[e] * r;
}

// ---------------- Kernel D2: build A_big from P and proj weights (grid (16, nb)) ----------------
__global__ __launch_bounds__(256) void k_M(const float* __restrict__ P,
                                           const float* __restrict__ pwr,
                                           const float* __restrict__ pwi,
                                           u16* __restrict__ Abig, int b0) {
    int b = b0 + blockIdx.y;
    int pair = blockIdx.x * 256 + threadIdx.x;   // 0..4095
    __shared__ float P0[64][64], P1[64][64];
    __shared__ float Wr[64][64], Wi2[64][64];
    for (int i = threadIdx.x; i < 4096; i += 256) {
        P0[i >> 6][i & 63] = P[(size_t)(b * 2 + 0) * 4096 + i];
        P1[i >> 6][i & 63] = P[(size_t)(b * 2 + 1) * 4096 + i];
        Wr[i >> 6][i & 63] = pwr[i];
        Wi2[i >> 6][i & 63] = pwi[i];
    }
    __syncthreads();
    int co = pair >> 6, e = pair & 63;
    float m1 = 0.f, m2 = 0.f, m3 = 0.f, m4 = 0.f;
#pragma unroll 8
    for (int c = 0; c < 64; ++c) {
        float pr = Wr[co][c], pi = Wi2[co][c];
        float a0 = P0[c][e], a1 = P1[c][e];
        m1 = fmaf(pr, a0, m1);
        m2 = fmaf(pi, a1, m2);
        m3 = fmaf(pr, a1, m3);
        m4 = fmaf(pi, a0, m4);
    }
    u16* AB = Abig + (size_t)b * 16384;
    AB[(2 * co) * 128 + 2 * e]         = f2bf(m1);
    AB[(2 * co) * 128 + 2 * e + 1]     = f2bf(-m2);
    AB[(2 * co + 1) * 128 + 2 * e]     = f2bf(m4);
    AB[(2 * co + 1) * 128 + 2 * e + 1] = f2bf(m3);
}

// ---------------- Kernel E (fallback): transpose vpack [64][HWS] u32 -> vT [HWS][64] u32 ----------------
__global__ __launch_bounds__(256) void k_vt(const u32* __restrict__ in,
                                            u32* __restrict__ outp) {
    __shared__ u32 tile[64][65];
    int p0 = blockIdx.x << 6;
    int t = threadIdx.x;
    for (int i = t; i < 4096; i += 256) {
        int e = i >> 6, c = i & 63;
        tile[e][c] = in[(size_t)e * HWS + p0 + c];
    }
    __syncthreads();
    for (int i = t; i < 4096; i += 256) {
        int r = i >> 6, e = i & 63;
        outp[(size_t)(p0 + r) * 64 + e] = tile[e][r];
    }
}

// ---------------- Kernel F (fallback): out = A_big * vT via MFMA (no LDS) ----------------
__global__ __launch_bounds__(256) void k_out(const u16* __restrict__ Abig,
                                             const u16* __restrict__ vT,
                                             float* __restrict__ outb) {
    const int p0 = blockIdx.x << 6;
    const int t = threadIdx.x, lane = t & 63, w = t >> 6;
    const int l15 = lane & 15, l4 = lane >> 4;

    bf16x8 Af[2][4];
#pragma unroll
    for (int cf = 0; cf < 2; ++cf)
#pragma unroll
        for (int ks = 0; ks < 4; ++ks)
            Af[cf][ks] = *(const bf16x8*)&Abig[(size_t)(32 * w + 16 * cf + l15) * 128 + 32 * ks + 8 * l4];

    f32x4 zz = {0.f, 0.f, 0.f, 0.f};
    f32x4 acc[2][4];
#pragma unroll
    for (int cf = 0; cf < 2; ++cf)
#pragma unroll
        for (int nf = 0; nf < 4; ++nf) acc[cf][nf] = zz;

#pragma unroll
    for (int ks = 0; ks < 4; ++ks) {
        bf16x8 Bf[4];
#pragma unroll
        for (int nf = 0; nf < 4; ++nf)
            Bf[nf] = *(const bf16x8*)&vT[(size_t)(p0 + 16 * nf + l15) * 128 + 32 * ks + 8 * l4];
#pragma unroll
        for (int cf = 0; cf < 2; ++cf)
#pragma unroll
            for (int nf = 0; nf < 4; ++nf)
                acc[cf][nf] = __builtin_amdgcn_mfma_f32_16x16x32_bf16(Af[cf][ks], Bf[nf], acc[cf][nf], 0, 0, 0);
    }

    float2* o2 = (float2*)outb;
#pragma unroll
    for (int cf = 0; cf < 2; ++cf)
#pragma unroll
        for (int nf = 0; nf < 4; ++nf) {
            int co = 16 * w + 8 * cf + 2 * l4;
            int p = p0 + 16 * nf + l15;
            o2[(size_t)co * HWS + p]       = make_float2(acc[cf][nf][0], acc[cf][nf][1]);
            o2[(size_t)(co + 1) * HWS + p] = make_float2(acc[cf][nf][2], acc[cf][nf][3]);
        }
}

// ---------------- Kernel F2: out = A_big * v via LDS-staged vpack ----------------
__global__ __launch_bounds__(256) void k_out2(const u16* __restrict__ Abig,
                                              const u32* __restrict__ vpk,
                                              float* __restrict__ outb,
                                              int b0, size_t vst, size_t ost) {
    const int z = blockIdx.z;
    const int b = b0 + z;
    vpk += (size_t)z * vst; outb += (size_t)z * ost;
    __shared__ u32 Tep[64][65];
    const int p0 = blockIdx.x << 6;
    const int t = threadIdx.x, lane = t & 63, w = t >> 6;
    const int l15 = lane & 15, l4 = lane >> 4;
    const u16* AB = Abig + (size_t)b * 16384;

    bf16x8 Af[2][4];
#pragma unroll
    for (int cf = 0; cf < 2; ++cf)
#pragma unroll
        for (int ks = 0; ks < 4; ++ks)
            Af[cf][ks] = *(const bf16x8*)&AB[(size_t)(32 * w + 16 * cf + l15) * 128 + 32 * ks + 8 * l4];

    for (int i = t; i < 4096; i += 256) {
        int e = i >> 6, tok = i & 63;
        Tep[e][tok] = vpk[(size_t)e * HWS + p0 + tok];
    }
    __syncthreads();

    f32x4 zz = {0.f, 0.f, 0.f, 0.f};
    f32x4 acc[2][4];
#pragma unroll
    for (int cf = 0; cf < 2; ++cf)
#pragma unroll
        for (int nf = 0; nf < 4; ++nf) acc[cf][nf] = zz;

#pragma unroll
    for (int ks = 0; ks < 4; ++ks) {
        bf16x8 Bf[4];
#pragma unroll
        for (int nf = 0; nf < 4; ++nf) {
            int tok = 16 * nf + l15;
            int e0 = 16 * ks + 4 * l4;
            union { u32 u[4]; bf16x8 v; } bb;
#pragma unroll
            for (int j = 0; j < 4; ++j) bb.u[j] = Tep[e0 + j][tok];
            Bf[nf] = bb.v;
        }
#pragma unroll
        for (int cf = 0; cf < 2; ++cf)
#pragma unroll
            for (int nf = 0; nf < 4; ++nf)
                acc[cf][nf] = __builtin_amdgcn_mfma_f32_16x16x32_bf16(Af[cf][ks], Bf[nf], acc[cf][nf], 0, 0, 0);
    }

    float2* o2 = (float2*)outb;
#pragma unroll
    for (int cf = 0; cf < 2; ++cf)
#pragma unroll
        for (int nf = 0; nf < 4; ++nf) {
            int co = 16 * w + 8 * cf + 2 * l4;
            int p = p0 + 16 * nf + l15;
            o2[(size_t)co * HWS + p]       = make_float2(acc[cf][nf][0], acc[cf][nf][1]);
            o2[(size_t)(co + 1) * HWS + p] = make_float2(acc[cf][nf][2], acc[cf][nf][3]);
        }
}

extern "C" void kernel_launch(void* const* d_in, const int* in_sizes, int n_in,
                              void* d_out, int out_size, void* d_ws, size_t ws_size,
                              hipStream_t stream) {
    const float* x      = (const float*)d_in[0];
    const float* qkv_wr = (const float*)d_in[1];
    const float* qkv_wi = (const float*)d_in[2];
    const float* dw_wr  = (const float*)d_in[3];
    const float* dw_wi  = (const float*)d_in[4];
    const float* p_wr   = (const float*)d_in[5];
    const float* p_wi   = (const float*)d_in[6];
    float* out = (float*)d_out;
    const size_t OSTR = (size_t)64 * HWS * 2;   // floats per batch of output

    const bool z2  = ws_size >= 236000000ull;   // fully per-b-strided buffers
    const bool f14 = !z2 && ws_size >= 118200000ull;

    char* base = (char*)d_ws;

    if (z2) {
        // per-b strided layout (~235.9 MB)
        u32*   qs   = (u32*)base;                          // 2 x 50,724,864 B
        u16*   dwp  = (u16*)(base + 101449728);            // 2 x 33,554,432 B
        u16*   xTr  = (u16*)(base + 168558592);            // 2 x (8.39+8.39) MB
        u16*   xTi  = xTr + (size_t)HWS * 64;
        u32*   vpk  = (u32*)(base + 202113024);            // 2 x 16,777,216 B
        u16*   wbf  = (u16*)(base + 235667456);
        float* rnsum = (float*)(base + 235741184);
        float* attn  = rnsum + 512;
        float* Pbuf  = attn + 16384;
        u16*   Abig  = (u16*)(Pbuf + 16384);

        const size_t XT_ST = 8388608;     // u16 per b (both planes)
        const size_t QS_ST = 12681216;    // u32 per b
        const size_t DW_ST = 16777216;    // u16 per b
        const size_t VP_ST = 4194304;     // u32 per b

        k_prep<<<66, 256, 0, stream>>>(qkv_wr, qkv_wi, wbf, rnsum, 512 + 16384);
        k_xt<<<dim3(1024, 1, 2), 256, 0, stream>>>(x, xTr, xTi, OSTR, XT_ST);
        k_qkv<<<dim3(6, 258, 2), 256, 0, stream>>>(xTr, xTi, wbf, qs, XT_ST, QS_ST);
        k_dw<<<dim3(12288, 1, 2), 256, 0, stream>>>(qs, dw_wr, dw_wi, dwp, vpk,
                                                    QS_ST, DW_ST, VP_ST);
        k_qk<<<dim3(64, 2, 2), 256, 0, stream>>>(dwp, rnsum, attn, 0, DW_ST);
        k_prob<<<dim3(2, 2), 64, 0, stream>>>(attn, rnsum, Pbuf, 0);
        k_M<<<dim3(16, 2), 256, 0, stream>>>(Pbuf, p_wr, p_wi, Abig, 0);
        k_out2<<<dim3(1024, 1, 2), 256, 0, stream>>>(Abig, vpk, out, 0, VP_ST, OSTR);
        return;
    }

    // shared-buffer layouts (round-14 / round-13 proven paths)
    u32*   qs   = (u32*)base;                               // 50,724,864 B
    u16*   dwp  = (u16*)(base + 50724864);                  // 33,554,432 B
    char*  xreg = base + 50724864 + 33554432;               // 16,777,216 B
    u16*   xTr  = (u16*)xreg;
    u16*   xTi  = xTr + (size_t)HWS * 64;
    u32*   vT   = (u32*)xreg;                               // fallback-13: vT aliases xT
    u32*   vpkW = (u32*)(base + 101056512);                 // f14 only
    size_t tail = f14 ? 117833728ull : 101056512ull;
    u16*   wbf  = (u16*)(base + tail);
    float* rnsum = (float*)(base + tail + 73728);
    float* attn  = rnsum + 512;
    float* Pbuf  = attn + 16384;
    u16*   Abig  = (u16*)(Pbuf + 16384);

    k_prep<<<66, 256, 0, stream>>>(qkv_wr, qkv_wi, wbf, rnsum, 512 + 16384);

    for (int b = 0; b < 2; ++b) {
        const float* xb = x + (size_t)b * OSTR;
        u32* vpack = f14 ? vpkW : (u32*)(out + (size_t)b * OSTR);
        k_xt<<<dim3(1024, 1, 1), 256, 0, stream>>>(xb, xTr, xTi, 0, 0);
        k_qkv<<<dim3(6, 258, 1), 256, 0, stream>>>(xTr, xTi, wbf, qs, 0, 0);
        k_dw<<<dim3(12288, 1, 1), 256, 0, stream>>>(qs, dw_wr, dw_wi, dwp, vpack, 0, 0, 0);
        k_qk<<<dim3(64, 2, 1), 256, 0, stream>>>(dwp, rnsum, attn, b, 0);
        k_prob<<<dim3(2, 1), 64, 0, stream>>>(attn, rnsum, Pbuf, b);
        k_M<<<dim3(16, 1), 256, 0, stream>>>(Pbuf, p_wr, p_wi, Abig, b);
        if (f14)
            k_out2<<<dim3(1024, 1, 1), 256, 0, stream>>>(Abig, vpkW,
                                                         out + (size_t)b * OSTR, b, 0, 0);
    }
    if (!f14) {
        for (int b = 0; b < 2; ++b) {
            u32* vpack = (u32*)(out + (size_t)b * OSTR);
            k_vt<<<1024, 256, 0, stream>>>(vpack, vT);
            k_out<<<1024, 256, 0, stream>>>(Abig + (size_t)b * 16384, (const u16*)vT,
                                            out + (size_t)b * OSTR);
        }
    }
}

// Round 17
// 189.284 us; speedup vs baseline: 2.5518x; 1.0937x over previous
//
#include <hip/hip_runtime.h>

#define HWS 65536   // 256*256
#define SPZ 66048   // (256+2)*256 halo strip positions

typedef __attribute__((ext_vector_type(8))) short bf16x8;
typedef __attribute__((ext_vector_type(4))) float f32x4;
typedef unsigned int u32;
typedef unsigned short u16;

__device__ __forceinline__ u16 f2bf(float x) {
    u32 u = __float_as_uint(x);
    return (u16)((u + 0x7fffu + ((u >> 16) & 1u)) >> 16);
}
__device__ __forceinline__ float bf2f(u32 h) { return __uint_as_float(h << 16); }
// HW packed bf16 convert (RNE, identical rounding to f2bf): lo=a, hi=b
__device__ __forceinline__ u32 cvtpk(float a, float b) {
    u32 r;
    asm("v_cvt_pk_bf16_f32 %0, %1, %2" : "=v"(r) : "v"(a), "v"(b));
    return r;
}

// ---------------- prep: weight cvt + zero accumulators (one launch) ----------------
__global__ void k_prep(const float* __restrict__ wr, const float* __restrict__ wi,
                       u16* __restrict__ wbf, float* __restrict__ zbuf, int nz) {
    int i = blockIdx.x * 256 + threadIdx.x;
    if (i < 12288) {
        wbf[i]         = f2bf(wr[i]);
        wbf[12288 + i] = f2bf(wi[i]);
        wbf[24576 + i] = f2bf(-wi[i]);
    }
    if (i < nz) zbuf[i] = 0.f;
}

// ---------------- Kernel X: transpose+convert x -> xTr/xTi bf16 [HWS][64] ----------------
__global__ __launch_bounds__(256) void k_xt(const float* __restrict__ x,
                                            u16* __restrict__ xTr,
                                            u16* __restrict__ xTi,
                                            size_t xs, size_t ts) {
    const int b = blockIdx.z;
    x += (size_t)b * xs; xTr += (size_t)b * ts; xTi += (size_t)b * ts;
    __shared__ u16 Tr[64][74], Ti[64][74];
    int p0 = blockIdx.x << 6;
    int t = threadIdx.x;
    const float2* x2 = (const float2*)x;
    for (int i = t; i < 2048; i += 256) {        // (ci-pair, c)
        int cp = i >> 6, c = i & 63;
        int ci = cp << 1;
        float2 v0 = x2[(size_t)ci * HWS + p0 + c];
        float2 v1 = x2[(size_t)(ci + 1) * HWS + p0 + c];
        *(u32*)&Tr[c][ci] = cvtpk(v0.x, v1.x);
        *(u32*)&Ti[c][ci] = cvtpk(v0.y, v1.y);
    }
    __syncthreads();
    for (int i = t; i < 2048; i += 256) {        // (row, ci-pair)
        int rr = i >> 5, cp = i & 31;
        *(u32*)&xTr[(size_t)(p0 + rr) * 64 + 2 * cp] = *(u32*)&Tr[rr][2 * cp];
        *(u32*)&xTi[(size_t)(p0 + rr) * 64 + 2 * cp] = *(u32*)&Ti[rr][2 * cp];
    }
}

// ---------------- Kernel A: qkv 1x1 complex conv, global->MFMA, no LDS ----------------
__global__ __launch_bounds__(256) void k_qkv(const u16* __restrict__ xTr,
                                             const u16* __restrict__ xTi,
                                             const u16* __restrict__ wbf,
                                             u32* __restrict__ qs,
                                             size_t ts, size_t qsst) {
    const int b = blockIdx.z;
    xTr += (size_t)b * ts; xTi += (size_t)b * ts; qs += (size_t)b * qsst;
    const int cog = blockIdx.x;          // 0..5, 32 co each
    const int rt  = blockIdx.y;          // 0..257
    const int w   = rt - 1;              // image row (may be OOB -> zeros)
    const int t = threadIdx.x, lane = t & 63, wv = t >> 6;
    const int l15 = lane & 15, l4 = lane >> 4;
    const bool valid = (unsigned)w < 256u;

    bf16x8 Ar[2][2], Ai[2][2], An[2][2];
#pragma unroll
    for (int cf = 0; cf < 2; ++cf)
#pragma unroll
        for (int ks = 0; ks < 2; ++ks) {
            size_t off = (size_t)(cog * 32 + 16 * cf + l15) * 64 + 32 * ks + 8 * l4;
            Ar[cf][ks] = *(const bf16x8*)&wbf[off];
            Ai[cf][ks] = *(const bf16x8*)&wbf[12288 + off];
            An[cf][ks] = *(const bf16x8*)&wbf[24576 + off];
        }

    const f32x4 zz = {0.f, 0.f, 0.f, 0.f};
#pragma unroll
    for (int pf = 0; pf < 4; ++pf) {
        f32x4 cr[2] = {zz, zz}, cim[2] = {zz, zz};
        if (valid) {
            bf16x8 br[2], bi[2];
#pragma unroll
            for (int ks = 0; ks < 2; ++ks) {
                size_t boff = (size_t)(w * 256 + wv * 64 + pf * 16 + l15) * 64
                              + 32 * ks + 8 * l4;
                br[ks] = *(const bf16x8*)&xTr[boff];
                bi[ks] = *(const bf16x8*)&xTi[boff];
            }
#pragma unroll
            for (int ks = 0; ks < 2; ++ks)
#pragma unroll
                for (int cf = 0; cf < 2; ++cf) {
                    cr[cf]  = __builtin_amdgcn_mfma_f32_16x16x32_bf16(Ar[cf][ks], br[ks], cr[cf], 0, 0, 0);
                    cr[cf]  = __builtin_amdgcn_mfma_f32_16x16x32_bf16(An[cf][ks], bi[ks], cr[cf], 0, 0, 0);
                    cim[cf] = __builtin_amdgcn_mfma_f32_16x16x32_bf16(Ai[cf][ks], br[ks], cim[cf], 0, 0, 0);
                    cim[cf] = __builtin_amdgcn_mfma_f32_16x16x32_bf16(Ar[cf][ks], bi[ks], cim[cf], 0, 0, 0);
                }
        }
        int p = rt * 256 + wv * 64 + pf * 16 + l15;
#pragma unroll
        for (int cf = 0; cf < 2; ++cf)
#pragma unroll
            for (int r = 0; r < 4; ++r) {
                int co = cog * 32 + 16 * cf + 4 * l4 + r;
                qs[(size_t)co * SPZ + p] = valid ? cvtpk(cr[cf][r], cim[cf][r]) : 0u;
            }
    }
}

// ---------------- Kernel B: depthwise 3x3 complex conv, 4 pixels/thread ----------------
// wave == one image row; uint4 loads + shfl halo. ch uniform per block.
__global__ __launch_bounds__(256) void k_dw(const u32* __restrict__ qs,
                                            const float* __restrict__ wr,
                                            const float* __restrict__ wi,
                                            u16* __restrict__ dwp,
                                            u32* __restrict__ vpack,
                                            size_t qsst, size_t dst, size_t vst) {
    const int b = blockIdx.z;
    qs += (size_t)b * qsst; dwp += (size_t)b * dst; vpack += (size_t)b * vst;
    const int ch = blockIdx.x >> 6;                         // uniform -> s_loads
    const int p4 = (((blockIdx.x & 63) << 8) + threadIdx.x) << 2;
    const int r = p4 >> 8, h = p4 & 255;                    // h = 4*laneInRow
    const u32* src = qs + (size_t)ch * SPZ + r * 256;

    float wrl[9], wil[9];
#pragma unroll
    for (int tt = 0; tt < 9; ++tt) { wrl[tt] = wr[ch * 9 + tt]; wil[tt] = wi[ch * 9 + tt]; }

    u32 uv[3][6];
#pragma unroll
    for (int du = 0; du < 3; ++du) {
        uint4 W = *(const uint4*)&src[du * 256 + h];        // coalesced 16B/lane
        u32 left  = (u32)__shfl_up((int)W.w, 1);            // word at h-1
        u32 right = (u32)__shfl_down((int)W.x, 1);          // word at h+4
        if (h == 0)   left = 0u;
        if (h == 252) right = 0u;
        uv[du][0] = left;  uv[du][1] = W.x; uv[du][2] = W.y;
        uv[du][3] = W.z;   uv[du][4] = W.w; uv[du][5] = right;
    }
    float vr[3][6], vi[3][6];
#pragma unroll
    for (int du = 0; du < 3; ++du)
#pragma unroll
        for (int j = 0; j < 6; ++j) {
            vr[du][j] = bf2f(uv[du][j] & 0xffffu);
            vi[du][j] = bf2f(uv[du][j] >> 16);
        }

    float ar[4] = {0.f, 0.f, 0.f, 0.f}, ai[4] = {0.f, 0.f, 0.f, 0.f};
#pragma unroll
    for (int du = 0; du < 3; ++du)
#pragma unroll
        for (int ct = 0; ct < 3; ++ct) {
            float w0 = wrl[du * 3 + ct], w1 = wil[du * 3 + ct];
#pragma unroll
            for (int px = 0; px < 4; ++px) {
                float xr = vr[du][px + ct], xi = vi[du][px + ct];
                ar[px] = fmaf(w0, xr, ar[px]); ar[px] = fmaf(-w1, xi, ar[px]);
                ai[px] = fmaf(w1, xr, ai[px]); ai[px] = fmaf(w0, xi, ai[px]);
            }
        }

    if (ch < 128) {
        int pl = (ch < 64) ? 0 : 2;
        int c2 = ch & 63;
        uint2 rw = make_uint2(cvtpk(ar[0], ar[1]), cvtpk(ar[2], ar[3]));
        uint2 iw = make_uint2(cvtpk(ai[0], ai[1]), cvtpk(ai[2], ai[3]));
        *(uint2*)&dwp[(size_t)(pl * 64 + c2) * HWS + p4] = rw;
        *(uint2*)&dwp[(size_t)((pl + 1) * 64 + c2) * HWS + p4] = iw;
    } else {
        int e = ch - 128;
        uint4 vv = make_uint4(cvtpk(ar[0], ai[0]), cvtpk(ar[1], ai[1]),
                              cvtpk(ar[2], ai[2]), cvtpk(ar[3], ai[3]));
        *(uint4*)&vpack[(size_t)e * HWS + p4] = vv;
    }
}

// ---------------- Kernel C: q k^T + fused sumsq via MFMA (no LDS) ----------------
// grid (64 chunks, 2 d, nb)
__global__ __launch_bounds__(256) void k_qk(const u16* __restrict__ dwp,
                                            float* __restrict__ rnsum,
                                            float* __restrict__ attn,
                                            int b0, size_t dst) {
    const int z = blockIdx.z;
    const int b = b0 + z;
    dwp += (size_t)z * dst;
    const int chunk = blockIdx.x;        // 0..63
    const int d = blockIdx.y;
    const int Kc = HWS >> 6;
    const int kc0 = chunk * Kc;
    const u16* qp = dwp + (size_t)d * 64 * HWS;
    const u16* kp = dwp + (size_t)(2 + d) * 64 * HWS;

    const int t = threadIdx.x, lane = t & 63, wid = t >> 6;
    const int wy = wid >> 1, wx = wid & 1;
    const int l15 = lane & 15, l4 = lane >> 4;

    f32x4 zz = {0.f, 0.f, 0.f, 0.f};
    f32x4 acc[2][2] = {{zz, zz}, {zz, zz}};
    float sq[2] = {0.f, 0.f}, sk[2] = {0.f, 0.f};

    const int iters = Kc >> 5;
    for (int ks = 0; ks < iters; ++ks) {
        int k0 = kc0 + ks * 32 + 8 * l4;
        bf16x8 aq[2], bk[2];
#pragma unroll
        for (int cf = 0; cf < 2; ++cf)
            aq[cf] = *(const bf16x8*)&qp[(size_t)(32 * wy + 16 * cf + l15) * HWS + k0];
#pragma unroll
        for (int ef = 0; ef < 2; ++ef)
            bk[ef] = *(const bf16x8*)&kp[(size_t)(32 * wx + 16 * ef + l15) * HWS + k0];

        if (wx == 0)
#pragma unroll
            for (int cf = 0; cf < 2; ++cf)
#pragma unroll
                for (int j = 0; j < 8; ++j) {
                    float f = bf2f((u16)aq[cf][j]);
                    sq[cf] = fmaf(f, f, sq[cf]);
                }
        if (wy == 0)
#pragma unroll
            for (int ef = 0; ef < 2; ++ef)
#pragma unroll
                for (int j = 0; j < 8; ++j) {
                    float f = bf2f((u16)bk[ef][j]);
                    sk[ef] = fmaf(f, f, sk[ef]);
                }

#pragma unroll
        for (int cf = 0; cf < 2; ++cf)
#pragma unroll
            for (int ef = 0; ef < 2; ++ef)
                acc[cf][ef] = __builtin_amdgcn_mfma_f32_16x16x32_bf16(aq[cf], bk[ef], acc[cf][ef], 0, 0, 0);
    }

#pragma unroll
    for (int cf = 0; cf < 2; ++cf)
#pragma unroll
        for (int ef = 0; ef < 2; ++ef)
#pragma unroll
            for (int r = 0; r < 4; ++r) {
                int cq = 32 * wy + 16 * cf + 4 * l4 + r;
                int ce = 32 * wx + 16 * ef + l15;
                atomicAdd(&attn[((b * 2 + d) * 64 + cq) * 64 + ce], acc[cf][ef][r]);
            }

    if (wx == 0)
#pragma unroll
        for (int cf = 0; cf < 2; ++cf) {
            float v = sq[cf];
            v += __shfl_xor(v, 16);
            v += __shfl_xor(v, 32);
            if (lane < 16)
                atomicAdd(&rnsum[((size_t)b * 128 + 32 * wy + 16 * cf + lane) * 2 + d], v);
        }
    if (wy == 0)
#pragma unroll
        for (int ef = 0; ef < 2; ++ef) {
            float v = sk[ef];
            v += __shfl_xor(v, 16);
            v += __shfl_xor(v, 32);
            if (lane < 16)
                atomicAdd(&rnsum[((size_t)b * 128 + 64 + 32 * wx + 16 * ef + lane) * 2 + d], v);
        }
}

// ---------------- Kernel D1: scale + row softmax -> P (grid (2 d, nb), 64 thr) ----------------
__global__ __launch_bounds__(64) void k_prob(const float* __restrict__ attn,
                                             const float* __restrict__ rnsum,
                                             float* __restrict__ P, int b0) {
    int d = blockIdx.x;
    int b = b0 + blockIdx.y;
    int t = threadIdx.x;
    __shared__ float rks[64];
    float sk = rnsum[((size_t)b * 128 + 64 + t) * 2 + d];
    rks[t] = 1.0f / fmaxf(sqrtf(sk), 1e-12f);
    float sq = rnsum[((size_t)b * 128 + t) * 2 + d];
    float rq = 1.0f / fmaxf(sqrtf(sq), 1e-12f);
    __syncthreads();

    const float* arow = attn + ((size_t)(b * 2 + d) * 64 + t) * 64;
    float v[64];
    float m = -1e30f;
#pragma unroll
    for (int e = 0; e < 64; ++e) { v[e] = arow[e] * rq * rks[e]; m = fmaxf(m, v[e]); }
    float ssum = 0.f;
#pragma unroll
    for (int e = 0; e < 64; ++e) { v[e] = __expf(v[e] - m); ssum += v[e]; }
    float r = 1.0f / ssum;
    float* prow = P + ((size_t)(b * 2 + d) * 64 + t) * 64;
#pragma unroll
    for (int e = 0; e < 64; ++e) prow[e] = v[e] * r;
}

// ---------------- Kernel D2: build A_big from P and proj weights (grid (16, nb)) ----------------
__global__ __launch_bounds__(256) void k_M(const float* __restrict__ P,
                                           const float* __restrict__ pwr,
                                           const float* __restrict__ pwi,
                                           u16* __restrict__ Abig, int b0) {
    int b = b0 + blockIdx.y;
    int pair = blockIdx.x * 256 + threadIdx.x;   // 0..4095
    __shared__ float P0[64][64], P1[64][64];
    __shared__ float Wr[64][64], Wi2[64][64];
    for (int i = threadIdx.x; i < 4096; i += 256) {
        P0[i >> 6][i & 63] = P[(size_t)(b * 2 + 0) * 4096 + i];
        P1[i >> 6][i & 63] = P[(size_t)(b * 2 + 1) * 4096 + i];
        Wr[i >> 6][i & 63] = pwr[i];
        Wi2[i >> 6][i & 63] = pwi[i];
    }
    __syncthreads();
    int co = pair >> 6, e = pair & 63;
    float m1 = 0.f, m2 = 0.f, m3 = 0.f, m4 = 0.f;
#pragma unroll 8
    for (int c = 0; c < 64; ++c) {
        float pr = Wr[co][c], pi = Wi2[co][c];
        float a0 = P0[c][e], a1 = P1[c][e];
        m1 = fmaf(pr, a0, m1);
        m2 = fmaf(pi, a1, m2);
        m3 = fmaf(pr, a1, m3);
        m4 = fmaf(pi, a0, m4);
    }
    u16* AB = Abig + (size_t)b * 16384;
    AB[(2 * co) * 128 + 2 * e]         = f2bf(m1);
    AB[(2 * co) * 128 + 2 * e + 1]     = f2bf(-m2);
    AB[(2 * co + 1) * 128 + 2 * e]     = f2bf(m4);
    AB[(2 * co + 1) * 128 + 2 * e + 1] = f2bf(m3);
}

// ---------------- Kernel E (fallback): transpose vpack [64][HWS] u32 -> vT [HWS][64] u32 ----------------
__global__ __launch_bounds__(256) void k_vt(const u32* __restrict__ in,
                                            u32* __restrict__ outp) {
    __shared__ u32 tile[64][65];
    int p0 = blockIdx.x << 6;
    int t = threadIdx.x;
    for (int i = t; i < 4096; i += 256) {
        int e = i >> 6, c = i & 63;
        tile[e][c] = in[(size_t)e * HWS + p0 + c];
    }
    __syncthreads();
    for (int i = t; i < 4096; i += 256) {
        int r = i >> 6, e = i & 63;
        outp[(size_t)(p0 + r) * 64 + e] = tile[e][r];
    }
}

// ---------------- Kernel F (fallback): out = A_big * vT via MFMA (no LDS) ----------------
__global__ __launch_bounds__(256) void k_out(const u16* __restrict__ Abig,
                                             const u16* __restrict__ vT,
                                             float* __restrict__ outb) {
    const int p0 = blockIdx.x << 6;
    const int t = threadIdx.x, lane = t & 63, w = t >> 6;
    const int l15 = lane & 15, l4 = lane >> 4;

    bf16x8 Af[2][4];
#pragma unroll
    for (int cf = 0; cf < 2; ++cf)
#pragma unroll
        for (int ks = 0; ks < 4; ++ks)
            Af[cf][ks] = *(const bf16x8*)&Abig[(size_t)(32 * w + 16 * cf + l15) * 128 + 32 * ks + 8 * l4];

    f32x4 zz = {0.f, 0.f, 0.f, 0.f};
    f32x4 acc[2][4];
#pragma unroll
    for (int cf = 0; cf < 2; ++cf)
#pragma unroll
        for (int nf = 0; nf < 4; ++nf) acc[cf][nf] = zz;

#pragma unroll
    for (int ks = 0; ks < 4; ++ks) {
        bf16x8 Bf[4];
#pragma unroll
        for (int nf = 0; nf < 4; ++nf)
            Bf[nf] = *(const bf16x8*)&vT[(size_t)(p0 + 16 * nf + l15) * 128 + 32 * ks + 8 * l4];
#pragma unroll
        for (int cf = 0; cf < 2; ++cf)
#pragma unroll
            for (int nf = 0; nf < 4; ++nf)
                acc[cf][nf] = __builtin_amdgcn_mfma_f32_16x16x32_bf16(Af[cf][ks], Bf[nf], acc[cf][nf], 0, 0, 0);
    }

    float2* o2 = (float2*)outb;
#pragma unroll
    for (int cf = 0; cf < 2; ++cf)
#pragma unroll
        for (int nf = 0; nf < 4; ++nf) {
            int co = 16 * w + 8 * cf + 2 * l4;
            int p = p0 + 16 * nf + l15;
            o2[(size_t)co * HWS + p]       = make_float2(acc[cf][nf][0], acc[cf][nf][1]);
            o2[(size_t)(co + 1) * HWS + p] = make_float2(acc[cf][nf][2], acc[cf][nf][3]);
        }
}

// ---------------- Kernel F2: out = A_big * v via LDS-staged vpack ----------------
__global__ __launch_bounds__(256) void k_out2(const u16* __restrict__ Abig,
                                              const u32* __restrict__ vpk,
                                              float* __restrict__ outb,
                                              int b0, size_t vst, size_t ost) {
    const int z = blockIdx.z;
    const int b = b0 + z;
    vpk += (size_t)z * vst; outb += (size_t)z * ost;
    __shared__ u32 Tep[64][65];
    const int p0 = blockIdx.x << 6;
    const int t = threadIdx.x, lane = t & 63, w = t >> 6;
    const int l15 = lane & 15, l4 = lane >> 4;
    const u16* AB = Abig + (size_t)b * 16384;

    bf16x8 Af[2][4];
#pragma unroll
    for (int cf = 0; cf < 2; ++cf)
#pragma unroll
        for (int ks = 0; ks < 4; ++ks)
            Af[cf][ks] = *(const bf16x8*)&AB[(size_t)(32 * w + 16 * cf + l15) * 128 + 32 * ks + 8 * l4];

    for (int i = t; i < 4096; i += 256) {
        int e = i >> 6, tok = i & 63;
        Tep[e][tok] = vpk[(size_t)e * HWS + p0 + tok];
    }
    __syncthreads();

    f32x4 zz = {0.f, 0.f, 0.f, 0.f};
    f32x4 acc[2][4];
#pragma unroll
    for (int cf = 0; cf < 2; ++cf)
#pragma unroll
        for (int nf = 0; nf < 4; ++nf) acc[cf][nf] = zz;

#pragma unroll
    for (int ks = 0; ks < 4; ++ks) {
        bf16x8 Bf[4];
#pragma unroll
        for (int nf = 0; nf < 4; ++nf) {
            int tok = 16 * nf + l15;
            int e0 = 16 * ks + 4 * l4;
            union { u32 u[4]; bf16x8 v; } bb;
#pragma unroll
            for (int j = 0; j < 4; ++j) bb.u[j] = Tep[e0 + j][tok];
            Bf[nf] = bb.v;
        }
#pragma unroll
        for (int cf = 0; cf < 2; ++cf)
#pragma unroll
            for (int nf = 0; nf < 4; ++nf)
                acc[cf][nf] = __builtin_amdgcn_mfma_f32_16x16x32_bf16(Af[cf][ks], Bf[nf], acc[cf][nf], 0, 0, 0);
    }

    float2* o2 = (float2*)outb;
#pragma unroll
    for (int cf = 0; cf < 2; ++cf)
#pragma unroll
        for (int nf = 0; nf < 4; ++nf) {
            int co = 16 * w + 8 * cf + 2 * l4;
            int p = p0 + 16 * nf + l15;
            o2[(size_t)co * HWS + p]       = make_float2(acc[cf][nf][0], acc[cf][nf][1]);
            o2[(size_t)(co + 1) * HWS + p] = make_float2(acc[cf][nf][2], acc[cf][nf][3]);
        }
}

extern "C" void kernel_launch(void* const* d_in, const int* in_sizes, int n_in,
                              void* d_out, int out_size, void* d_ws, size_t ws_size,
                              hipStream_t stream) {
    const float* x      = (const float*)d_in[0];
    const float* qkv_wr = (const float*)d_in[1];
    const float* qkv_wi = (const float*)d_in[2];
    const float* dw_wr  = (const float*)d_in[3];
    const float* dw_wi  = (const float*)d_in[4];
    const float* p_wr   = (const float*)d_in[5];
    const float* p_wi   = (const float*)d_in[6];
    float* out = (float*)d_out;
    const size_t OSTR = (size_t)64 * HWS * 2;   // floats per batch of output

    const bool z2  = ws_size >= 236000000ull;   // fully per-b-strided buffers
    const bool f14 = !z2 && ws_size >= 118200000ull;

    char* base = (char*)d_ws;

    if (z2) {
        // per-b strided layout (~235.9 MB)
        u32*   qs   = (u32*)base;                          // 2 x 50,724,864 B
        u16*   dwp  = (u16*)(base + 101449728);            // 2 x 33,554,432 B
        u16*   xTr  = (u16*)(base + 168558592);            // 2 x (8.39+8.39) MB
        u16*   xTi  = xTr + (size_t)HWS * 64;
        u32*   vpk  = (u32*)(base + 202113024);            // 2 x 16,777,216 B
        u16*   wbf  = (u16*)(base + 235667456);
        float* rnsum = (float*)(base + 235741184);
        float* attn  = rnsum + 512;
        float* Pbuf  = attn + 16384;
        u16*   Abig  = (u16*)(Pbuf + 16384);

        const size_t XT_ST = 8388608;     // u16 per b (both planes)
        const size_t QS_ST = 12681216;    // u32 per b
        const size_t DW_ST = 16777216;    // u16 per b
        const size_t VP_ST = 4194304;     // u32 per b

        k_prep<<<66, 256, 0, stream>>>(qkv_wr, qkv_wi, wbf, rnsum, 512 + 16384);
        k_xt<<<dim3(1024, 1, 2), 256, 0, stream>>>(x, xTr, xTi, OSTR, XT_ST);
        k_qkv<<<dim3(6, 258, 2), 256, 0, stream>>>(xTr, xTi, wbf, qs, XT_ST, QS_ST);
        k_dw<<<dim3(12288, 1, 2), 256, 0, stream>>>(qs, dw_wr, dw_wi, dwp, vpk,
                                                    QS_ST, DW_ST, VP_ST);
        k_qk<<<dim3(64, 2, 2), 256, 0, stream>>>(dwp, rnsum, attn, 0, DW_ST);
        k_prob<<<dim3(2, 2), 64, 0, stream>>>(attn, rnsum, Pbuf, 0);
        k_M<<<dim3(16, 2), 256, 0, stream>>>(Pbuf, p_wr, p_wi, Abig, 0);
        k_out2<<<dim3(1024, 1, 2), 256, 0, stream>>>(Abig, vpk, out, 0, VP_ST, OSTR);
        return;
    }

    // shared-buffer layouts (round-14 / round-13 proven paths)
    u32*   qs   = (u32*)base;                               // 50,724,864 B
    u16*   dwp  = (u16*)(base + 50724864);                  // 33,554,432 B
    char*  xreg = base + 50724864 + 33554432;               // 16,777,216 B
    u16*   xTr  = (u16*)xreg;
    u16*   xTi  = xTr + (size_t)HWS * 64;
    u32*   vT   = (u32*)xreg;                               // fallback-13: vT aliases xT
    u32*   vpkW = (u32*)(base + 101056512);                 // f14 only
    size_t tail = f14 ? 117833728ull : 101056512ull;
    u16*   wbf  = (u16*)(base + tail);
    float* rnsum = (float*)(base + tail + 73728);
    float* attn  = rnsum + 512;
    float* Pbuf  = attn + 16384;
    u16*   Abig  = (u16*)(Pbuf + 16384);

    k_prep<<<66, 256, 0, stream>>>(qkv_wr, qkv_wi, wbf, rnsum, 512 + 16384);

    for (int b = 0; b < 2; ++b) {
        const float* xb = x + (size_t)b * OSTR;
        u32* vpack = f14 ? vpkW : (u32*)(out + (size_t)b * OSTR);
        k_xt<<<dim3(1024, 1, 1), 256, 0, stream>>>(xb, xTr, xTi, 0, 0);
        k_qkv<<<dim3(6, 258, 1), 256, 0, stream>>>(xTr, xTi, wbf, qs, 0, 0);
        k_dw<<<dim3(12288, 1, 1), 256, 0, stream>>>(qs, dw_wr, dw_wi, dwp, vpack, 0, 0, 0);
        k_qk<<<dim3(64, 2, 1), 256, 0, stream>>>(dwp, rnsum, attn, b, 0);
        k_prob<<<dim3(2, 1), 64, 0, stream>>>(attn, rnsum, Pbuf, b);
        k_M<<<dim3(16, 1), 256, 0, stream>>>(Pbuf, p_wr, p_wi, Abig, b);
        if (f14)
            k_out2<<<dim3(1024, 1, 1), 256, 0, stream>>>(Abig, vpkW,
                                                         out + (size_t)b * OSTR, b, 0, 0);
    }
    if (!f14) {
        for (int b = 0; b < 2; ++b) {
            u32* vpack = (u32*)(out + (size_t)b * OSTR);
            k_vt<<<1024, 256, 0, stream>>>(vpack, vT);
            k_out<<<1024, 256, 0, stream>>>(Abig + (size_t)b * 16384, (const u16*)vT,
                                            out + (size_t)b * OSTR);
        }
    }
}

// Round 18
// 179.545 us; speedup vs baseline: 2.6902x; 1.0542x over previous
//
#include <hip/hip_runtime.h>

#define HWS 65536   // 256*256
#define SPZ 66048   // (256+2)*256 halo strip positions

typedef __attribute__((ext_vector_type(8))) short bf16x8;
typedef __attribute__((ext_vector_type(4))) float f32x4;
typedef unsigned int u32;
typedef unsigned short u16;

__device__ __forceinline__ u16 f2bf(float x) {
    u32 u = __float_as_uint(x);
    return (u16)((u + 0x7fffu + ((u >> 16) & 1u)) >> 16);
}
__device__ __forceinline__ float bf2f(u32 h) { return __uint_as_float(h << 16); }
// HW packed bf16 convert (RNE, identical rounding to f2bf): lo=a, hi=b
__device__ __forceinline__ u32 cvtpk(float a, float b) {
    u32 r;
    asm("v_cvt_pk_bf16_f32 %0, %1, %2" : "=v"(r) : "v"(a), "v"(b));
    return r;
}

// ---------------- prep: weight cvt + zero accumulators (one launch) ----------------
__global__ void k_prep(const float* __restrict__ wr, const float* __restrict__ wi,
                       u16* __restrict__ wbf, float* __restrict__ zbuf, int nz) {
    int i = blockIdx.x * 256 + threadIdx.x;
    if (i < 12288) {
        wbf[i]         = f2bf(wr[i]);
        wbf[12288 + i] = f2bf(wi[i]);
        wbf[24576 + i] = f2bf(-wi[i]);
    }
    if (i < nz) zbuf[i] = 0.f;
}

// ---------------- Kernel X: transpose+convert x -> xTr/xTi bf16 [HWS][64] ----------------
__global__ __launch_bounds__(256) void k_xt(const float* __restrict__ x,
                                            u16* __restrict__ xTr,
                                            u16* __restrict__ xTi,
                                            size_t xs, size_t ts) {
    const int b = blockIdx.z;
    x += (size_t)b * xs; xTr += (size_t)b * ts; xTi += (size_t)b * ts;
    __shared__ u16 Tr[64][74], Ti[64][74];
    int p0 = blockIdx.x << 6;
    int t = threadIdx.x;
    const float2* x2 = (const float2*)x;
    for (int i = t; i < 2048; i += 256) {        // (ci-pair, c)
        int cp = i >> 6, c = i & 63;
        int ci = cp << 1;
        float2 v0 = x2[(size_t)ci * HWS + p0 + c];
        float2 v1 = x2[(size_t)(ci + 1) * HWS + p0 + c];
        *(u32*)&Tr[c][ci] = cvtpk(v0.x, v1.x);
        *(u32*)&Ti[c][ci] = cvtpk(v0.y, v1.y);
    }
    __syncthreads();
    for (int i = t; i < 2048; i += 256) {        // (row, ci-pair)
        int rr = i >> 5, cp = i & 31;
        *(u32*)&xTr[(size_t)(p0 + rr) * 64 + 2 * cp] = *(u32*)&Tr[rr][2 * cp];
        *(u32*)&xTi[(size_t)(p0 + rr) * 64 + 2 * cp] = *(u32*)&Ti[rr][2 * cp];
    }
}

// ---------------- Kernel A: qkv 1x1 complex conv, global->MFMA, no LDS ----------------
// 1D grid, XCD-swizzled: all 6 cog-blocks of a row-pair land on the same XCD.
// NPR = 258*nb row-pairs; grid.x = 8*6*ceil(NPR/8).
__global__ __launch_bounds__(256) void k_qkv(const u16* __restrict__ xTr,
                                             const u16* __restrict__ xTi,
                                             const u16* __restrict__ wbf,
                                             u32* __restrict__ qs,
                                             size_t ts, size_t qsst, int NPR) {
    const int bid = blockIdx.x;
    const int xcd = bid & 7, j = bid >> 3;
    const int cog = j % 6;               // 0..5, 32 co each
    const int pr  = xcd + 8 * (j / 6);   // row-pair index
    if (pr >= NPR) return;
    const int z  = pr / 258;
    const int rt = pr % 258;             // 0..257
    xTr += (size_t)z * ts; xTi += (size_t)z * ts; qs += (size_t)z * qsst;
    const int w = rt - 1;                // image row (may be OOB -> zeros)
    const int t = threadIdx.x, lane = t & 63, wv = t >> 6;
    const int l15 = lane & 15, l4 = lane >> 4;
    const bool valid = (unsigned)w < 256u;

    bf16x8 Ar[2][2], Ai[2][2], An[2][2];
#pragma unroll
    for (int cf = 0; cf < 2; ++cf)
#pragma unroll
        for (int ks = 0; ks < 2; ++ks) {
            size_t off = (size_t)(cog * 32 + 16 * cf + l15) * 64 + 32 * ks + 8 * l4;
            Ar[cf][ks] = *(const bf16x8*)&wbf[off];
            Ai[cf][ks] = *(const bf16x8*)&wbf[12288 + off];
            An[cf][ks] = *(const bf16x8*)&wbf[24576 + off];
        }

    const f32x4 zz = {0.f, 0.f, 0.f, 0.f};
#pragma unroll
    for (int pf = 0; pf < 4; ++pf) {
        f32x4 cr[2] = {zz, zz}, cim[2] = {zz, zz};
        if (valid) {
            bf16x8 br[2], bi[2];
#pragma unroll
            for (int ks = 0; ks < 2; ++ks) {
                size_t boff = (size_t)(w * 256 + wv * 64 + pf * 16 + l15) * 64
                              + 32 * ks + 8 * l4;
                br[ks] = *(const bf16x8*)&xTr[boff];
                bi[ks] = *(const bf16x8*)&xTi[boff];
            }
#pragma unroll
            for (int ks = 0; ks < 2; ++ks)
#pragma unroll
                for (int cf = 0; cf < 2; ++cf) {
                    cr[cf]  = __builtin_amdgcn_mfma_f32_16x16x32_bf16(Ar[cf][ks], br[ks], cr[cf], 0, 0, 0);
                    cr[cf]  = __builtin_amdgcn_mfma_f32_16x16x32_bf16(An[cf][ks], bi[ks], cr[cf], 0, 0, 0);
                    cim[cf] = __builtin_amdgcn_mfma_f32_16x16x32_bf16(Ai[cf][ks], br[ks], cim[cf], 0, 0, 0);
                    cim[cf] = __builtin_amdgcn_mfma_f32_16x16x32_bf16(Ar[cf][ks], bi[ks], cim[cf], 0, 0, 0);
                }
        }
        int p = rt * 256 + wv * 64 + pf * 16 + l15;
#pragma unroll
        for (int cf = 0; cf < 2; ++cf)
#pragma unroll
            for (int r = 0; r < 4; ++r) {
                int co = cog * 32 + 16 * cf + 4 * l4 + r;
                qs[(size_t)co * SPZ + p] = valid ? cvtpk(cr[cf][r], cim[cf][r]) : 0u;
            }
    }
}

// ---------------- Kernel B: depthwise 3x3 complex conv, 4 pixels/thread ----------------
// wave == one image row; uint4 loads + shfl halo. ch uniform per block.
__global__ __launch_bounds__(256) void k_dw(const u32* __restrict__ qs,
                                            const float* __restrict__ wr,
                                            const float* __restrict__ wi,
                                            u16* __restrict__ dwp,
                                            u32* __restrict__ vpack,
                                            size_t qsst, size_t dst, size_t vst) {
    const int b = blockIdx.z;
    qs += (size_t)b * qsst; dwp += (size_t)b * dst; vpack += (size_t)b * vst;
    const int ch = blockIdx.x >> 6;                         // uniform -> s_loads
    const int p4 = (((blockIdx.x & 63) << 8) + threadIdx.x) << 2;
    const int r = p4 >> 8, h = p4 & 255;                    // h = 4*laneInRow
    const u32* src = qs + (size_t)ch * SPZ + r * 256;

    float wrl[9], wil[9];
#pragma unroll
    for (int tt = 0; tt < 9; ++tt) { wrl[tt] = wr[ch * 9 + tt]; wil[tt] = wi[ch * 9 + tt]; }

    u32 uv[3][6];
#pragma unroll
    for (int du = 0; du < 3; ++du) {
        uint4 W = *(const uint4*)&src[du * 256 + h];        // coalesced 16B/lane
        u32 left  = (u32)__shfl_up((int)W.w, 1);            // word at h-1
        u32 right = (u32)__shfl_down((int)W.x, 1);          // word at h+4
        if (h == 0)   left = 0u;
        if (h == 252) right = 0u;
        uv[du][0] = left;  uv[du][1] = W.x; uv[du][2] = W.y;
        uv[du][3] = W.z;   uv[du][4] = W.w; uv[du][5] = right;
    }
    float vr[3][6], vi[3][6];
#pragma unroll
    for (int du = 0; du < 3; ++du)
#pragma unroll
        for (int j = 0; j < 6; ++j) {
            vr[du][j] = bf2f(uv[du][j] & 0xffffu);
            vi[du][j] = bf2f(uv[du][j] >> 16);
        }

    float ar[4] = {0.f, 0.f, 0.f, 0.f}, ai[4] = {0.f, 0.f, 0.f, 0.f};
#pragma unroll
    for (int du = 0; du < 3; ++du)
#pragma unroll
        for (int ct = 0; ct < 3; ++ct) {
            float w0 = wrl[du * 3 + ct], w1 = wil[du * 3 + ct];
#pragma unroll
            for (int px = 0; px < 4; ++px) {
                float xr = vr[du][px + ct], xi = vi[du][px + ct];
                ar[px] = fmaf(w0, xr, ar[px]); ar[px] = fmaf(-w1, xi, ar[px]);
                ai[px] = fmaf(w1, xr, ai[px]); ai[px] = fmaf(w0, xi, ai[px]);
            }
        }

    if (ch < 128) {
        int pl = (ch < 64) ? 0 : 2;
        int c2 = ch & 63;
        uint2 rw = make_uint2(cvtpk(ar[0], ar[1]), cvtpk(ar[2], ar[3]));
        uint2 iw = make_uint2(cvtpk(ai[0], ai[1]), cvtpk(ai[2], ai[3]));
        *(uint2*)&dwp[(size_t)(pl * 64 + c2) * HWS + p4] = rw;
        *(uint2*)&dwp[(size_t)((pl + 1) * 64 + c2) * HWS + p4] = iw;
    } else {
        int e = ch - 128;
        uint4 vv = make_uint4(cvtpk(ar[0], ai[0]), cvtpk(ar[1], ai[1]),
                              cvtpk(ar[2], ai[2]), cvtpk(ar[3], ai[3]));
        *(uint4*)&vpack[(size_t)e * HWS + p4] = vv;
    }
}

// ---------------- Kernel C: q k^T + fused sumsq via MFMA (no LDS) ----------------
// grid (64 chunks, 2 d, nb)
__global__ __launch_bounds__(256) void k_qk(const u16* __restrict__ dwp,
                                            float* __restrict__ rnsum,
                                            float* __restrict__ attn,
                                            int b0, size_t dst) {
    const int z = blockIdx.z;
    const int b = b0 + z;
    dwp += (size_t)z * dst;
    const int chunk = blockIdx.x;        // 0..63
    const int d = blockIdx.y;
    const int Kc = HWS >> 6;
    const int kc0 = chunk * Kc;
    const u16* qp = dwp + (size_t)d * 64 * HWS;
    const u16* kp = dwp + (size_t)(2 + d) * 64 * HWS;

    const int t = threadIdx.x, lane = t & 63, wid = t >> 6;
    const int wy = wid >> 1, wx = wid & 1;
    const int l15 = lane & 15, l4 = lane >> 4;

    f32x4 zz = {0.f, 0.f, 0.f, 0.f};
    f32x4 acc[2][2] = {{zz, zz}, {zz, zz}};
    float sq[2] = {0.f, 0.f}, sk[2] = {0.f, 0.f};

    const int iters = Kc >> 5;
    for (int ks = 0; ks < iters; ++ks) {
        int k0 = kc0 + ks * 32 + 8 * l4;
        bf16x8 aq[2], bk[2];
#pragma unroll
        for (int cf = 0; cf < 2; ++cf)
            aq[cf] = *(const bf16x8*)&qp[(size_t)(32 * wy + 16 * cf + l15) * HWS + k0];
#pragma unroll
        for (int ef = 0; ef < 2; ++ef)
            bk[ef] = *(const bf16x8*)&kp[(size_t)(32 * wx + 16 * ef + l15) * HWS + k0];

        if (wx == 0)
#pragma unroll
            for (int cf = 0; cf < 2; ++cf)
#pragma unroll
                for (int j = 0; j < 8; ++j) {
                    float f = bf2f((u16)aq[cf][j]);
                    sq[cf] = fmaf(f, f, sq[cf]);
                }
        if (wy == 0)
#pragma unroll
            for (int ef = 0; ef < 2; ++ef)
#pragma unroll
                for (int j = 0; j < 8; ++j) {
                    float f = bf2f((u16)bk[ef][j]);
                    sk[ef] = fmaf(f, f, sk[ef]);
                }

#pragma unroll
        for (int cf = 0; cf < 2; ++cf)
#pragma unroll
            for (int ef = 0; ef < 2; ++ef)
                acc[cf][ef] = __builtin_amdgcn_mfma_f32_16x16x32_bf16(aq[cf], bk[ef], acc[cf][ef], 0, 0, 0);
    }

#pragma unroll
    for (int cf = 0; cf < 2; ++cf)
#pragma unroll
        for (int ef = 0; ef < 2; ++ef)
#pragma unroll
            for (int r = 0; r < 4; ++r) {
                int cq = 32 * wy + 16 * cf + 4 * l4 + r;
                int ce = 32 * wx + 16 * ef + l15;
                atomicAdd(&attn[((b * 2 + d) * 64 + cq) * 64 + ce], acc[cf][ef][r]);
            }

    if (wx == 0)
#pragma unroll
        for (int cf = 0; cf < 2; ++cf) {
            float v = sq[cf];
            v += __shfl_xor(v, 16);
            v += __shfl_xor(v, 32);
            if (lane < 16)
                atomicAdd(&rnsum[((size_t)b * 128 + 32 * wy + 16 * cf + lane) * 2 + d], v);
        }
    if (wy == 0)
#pragma unroll
        for (int ef = 0; ef < 2; ++ef) {
            float v = sk[ef];
            v += __shfl_xor(v, 16);
            v += __shfl_xor(v, 32);
            if (lane < 16)
                atomicAdd(&rnsum[((size_t)b * 128 + 64 + 32 * wx + 16 * ef + lane) * 2 + d], v);
        }
}

// ---------------- Kernel D1: scale + row softmax -> P (grid (2 d, nb), 64 thr) ----------------
__global__ __launch_bounds__(64) void k_prob(const float* __restrict__ attn,
                                             const float* __restrict__ rnsum,
                                             float* __restrict__ P, int b0) {
    int d = blockIdx.x;
    int b = b0 + blockIdx.y;
    int t = threadIdx.x;
    __shared__ float rks[64];
    float sk = rnsum[((size_t)b * 128 + 64 + t) * 2 + d];
    rks[t] = 1.0f / fmaxf(sqrtf(sk), 1e-12f);
    float sq = rnsum[((size_t)b * 128 + t) * 2 + d];
    float rq = 1.0f / fmaxf(sqrtf(sq), 1e-12f);
    __syncthreads();

    const float* arow = attn + ((size_t)(b * 2 + d) * 64 + t) * 64;
    float v[64];
    float m = -1e30f;
#pragma unroll
    for (int e = 0; e < 64; ++e) { v[e] = arow[e] * rq * rks[e]; m = fmaxf(m, v[e]); }
    float ssum = 0.f;
#pragma unroll
    for (int e = 0; e < 64; ++e) { v[e] = __expf(v[e] - m); ssum += v[e]; }
    float r = 1.0f / ssum;
    float* prow = P + ((size_t)(b * 2 + d) * 64 + t) * 64;
#pragma unroll
    for (int e = 0; e < 64; ++e) prow[e] = v[e] * r;
}

// ---------------- Kernel D2: build A_big from P and proj weights (grid (16, nb)) ----------------
__global__ __launch_bounds__(256) void k_M(const float* __restrict__ P,
                                           const float* __restrict__ pwr,
                                           const float* __restrict__ pwi,
                                           u16* __restrict__ Abig, int b0) {
    int b = b0 + blockIdx.y;
    int pair = blockIdx.x * 256 + threadIdx.x;   // 0..4095
    __shared__ float P0[64][64], P1[64][64];
    __shared__ float Wr[64][64], Wi2[64][64];
    for (int i = threadIdx.x; i < 4096; i += 256) {
        P0[i >> 6][i & 63] = P[(size_t)(b * 2 + 0) * 4096 + i];
        P1[i >> 6][i & 63] = P[(size_t)(b * 2 + 1) * 4096 + i];
        Wr[i >> 6][i & 63] = pwr[i];
        Wi2[i >> 6][i & 63] = pwi[i];
    }
    __syncthreads();
    int co = pair >> 6, e = pair & 63;
    float m1 = 0.f, m2 = 0.f, m3 = 0.f, m4 = 0.f;
#pragma unroll 8
    for (int c = 0; c < 64; ++c) {
        float pr = Wr[co][c], pi = Wi2[co][c];
        float a0 = P0[c][e], a1 = P1[c][e];
        m1 = fmaf(pr, a0, m1);
        m2 = fmaf(pi, a1, m2);
        m3 = fmaf(pr, a1, m3);
        m4 = fmaf(pi, a0, m4);
    }
    u16* AB = Abig + (size_t)b * 16384;
    AB[(2 * co) * 128 + 2 * e]         = f2bf(m1);
    AB[(2 * co) * 128 + 2 * e + 1]     = f2bf(-m2);
    AB[(2 * co + 1) * 128 + 2 * e]     = f2bf(m4);
    AB[(2 * co + 1) * 128 + 2 * e + 1] = f2bf(m3);
}

// ---------------- Kernel E (fallback): transpose vpack [64][HWS] u32 -> vT [HWS][64] u32 ----------------
__global__ __launch_bounds__(256) void k_vt(const u32* __restrict__ in,
                                            u32* __restrict__ outp) {
    __shared__ u32 tile[64][65];
    int p0 = blockIdx.x << 6;
    int t = threadIdx.x;
    for (int i = t; i < 4096; i += 256) {
        int e = i >> 6, c = i & 63;
        tile[e][c] = in[(size_t)e * HWS + p0 + c];
    }
    __syncthreads();
    for (int i = t; i < 4096; i += 256) {
        int r = i >> 6, e = i & 63;
        outp[(size_t)(p0 + r) * 64 + e] = tile[e][r];
    }
}

// ---------------- Kernel F (fallback): out = A_big * vT via MFMA (no LDS) ----------------
__global__ __launch_bounds__(256) void k_out(const u16* __restrict__ Abig,
                                             const u16* __restrict__ vT,
                                             float* __restrict__ outb) {
    const int p0 = blockIdx.x << 6;
    const int t = threadIdx.x, lane = t & 63, w = t >> 6;
    const int l15 = lane & 15, l4 = lane >> 4;

    bf16x8 Af[2][4];
#pragma unroll
    for (int cf = 0; cf < 2; ++cf)
#pragma unroll
        for (int ks = 0; ks < 4; ++ks)
            Af[cf][ks] = *(const bf16x8*)&Abig[(size_t)(32 * w + 16 * cf + l15) * 128 + 32 * ks + 8 * l4];

    f32x4 zz = {0.f, 0.f, 0.f, 0.f};
    f32x4 acc[2][4];
#pragma unroll
    for (int cf = 0; cf < 2; ++cf)
#pragma unroll
        for (int nf = 0; nf < 4; ++nf) acc[cf][nf] = zz;

#pragma unroll
    for (int ks = 0; ks < 4; ++ks) {
        bf16x8 Bf[4];
#pragma unroll
        for (int nf = 0; nf < 4; ++nf)
            Bf[nf] = *(const bf16x8*)&vT[(size_t)(p0 + 16 * nf + l15) * 128 + 32 * ks + 8 * l4];
#pragma unroll
        for (int cf = 0; cf < 2; ++cf)
#pragma unroll
            for (int nf = 0; nf < 4; ++nf)
                acc[cf][nf] = __builtin_amdgcn_mfma_f32_16x16x32_bf16(Af[cf][ks], Bf[nf], acc[cf][nf], 0, 0, 0);
    }

    float2* o2 = (float2*)outb;
#pragma unroll
    for (int cf = 0; cf < 2; ++cf)
#pragma unroll
        for (int nf = 0; nf < 4; ++nf) {
            int co = 16 * w + 8 * cf + 2 * l4;
            int p = p0 + 16 * nf + l15;
            o2[(size_t)co * HWS + p]       = make_float2(acc[cf][nf][0], acc[cf][nf][1]);
            o2[(size_t)(co + 1) * HWS + p] = make_float2(acc[cf][nf][2], acc[cf][nf][3]);
        }
}

// ---------------- Kernel F2: out = A_big * v via LDS-staged vpack ----------------
__global__ __launch_bounds__(256) void k_out2(const u16* __restrict__ Abig,
                                              const u32* __restrict__ vpk,
                                              float* __restrict__ outb,
                                              int b0, size_t vst, size_t ost) {
    const int z = blockIdx.z;
    const int b = b0 + z;
    vpk += (size_t)z * vst; outb += (size_t)z * ost;
    __shared__ u32 Tep[64][65];
    const int p0 = blockIdx.x << 6;
    const int t = threadIdx.x, lane = t & 63, w = t >> 6;
    const int l15 = lane & 15, l4 = lane >> 4;
    const u16* AB = Abig + (size_t)b * 16384;

    bf16x8 Af[2][4];
#pragma unroll
    for (int cf = 0; cf < 2; ++cf)
#pragma unroll
        for (int ks = 0; ks < 4; ++ks)
            Af[cf][ks] = *(const bf16x8*)&AB[(size_t)(32 * w + 16 * cf + l15) * 128 + 32 * ks + 8 * l4];

    for (int i = t; i < 4096; i += 256) {
        int e = i >> 6, tok = i & 63;
        Tep[e][tok] = vpk[(size_t)e * HWS + p0 + tok];
    }
    __syncthreads();

    f32x4 zz = {0.f, 0.f, 0.f, 0.f};
    f32x4 acc[2][4];
#pragma unroll
    for (int cf = 0; cf < 2; ++cf)
#pragma unroll
        for (int nf = 0; nf < 4; ++nf) acc[cf][nf] = zz;

#pragma unroll
    for (int ks = 0; ks < 4; ++ks) {
        bf16x8 Bf[4];
#pragma unroll
        for (int nf = 0; nf < 4; ++nf) {
            int tok = 16 * nf + l15;
            int e0 = 16 * ks + 4 * l4;
            union { u32 u[4]; bf16x8 v; } bb;
#pragma unroll
            for (int j = 0; j < 4; ++j) bb.u[j] = Tep[e0 + j][tok];
            Bf[nf] = bb.v;
        }
#pragma unroll
        for (int cf = 0; cf < 2; ++cf)
#pragma unroll
            for (int nf = 0; nf < 4; ++nf)
                acc[cf][nf] = __builtin_amdgcn_mfma_f32_16x16x32_bf16(Af[cf][ks], Bf[nf], acc[cf][nf], 0, 0, 0);
    }

    float2* o2 = (float2*)outb;
#pragma unroll
    for (int cf = 0; cf < 2; ++cf)
#pragma unroll
        for (int nf = 0; nf < 4; ++nf) {
            int co = 16 * w + 8 * cf + 2 * l4;
            int p = p0 + 16 * nf + l15;
            o2[(size_t)co * HWS + p]       = make_float2(acc[cf][nf][0], acc[cf][nf][1]);
            o2[(size_t)(co + 1) * HWS + p] = make_float2(acc[cf][nf][2], acc[cf][nf][3]);
        }
}

extern "C" void kernel_launch(void* const* d_in, const int* in_sizes, int n_in,
                              void* d_out, int out_size, void* d_ws, size_t ws_size,
                              hipStream_t stream) {
    const float* x      = (const float*)d_in[0];
    const float* qkv_wr = (const float*)d_in[1];
    const float* qkv_wi = (const float*)d_in[2];
    const float* dw_wr  = (const float*)d_in[3];
    const float* dw_wi  = (const float*)d_in[4];
    const float* p_wr   = (const float*)d_in[5];
    const float* p_wi   = (const float*)d_in[6];
    float* out = (float*)d_out;
    const size_t OSTR = (size_t)64 * HWS * 2;   // floats per batch of output

    const bool z2  = ws_size >= 236000000ull;   // fully per-b-strided buffers
    const bool f14 = !z2 && ws_size >= 118200000ull;

    char* base = (char*)d_ws;

    if (z2) {
        // per-b strided layout (~235.9 MB)
        u32*   qs   = (u32*)base;                          // 2 x 50,724,864 B
        u16*   dwp  = (u16*)(base + 101449728);            // 2 x 33,554,432 B
        u16*   xTr  = (u16*)(base + 168558592);            // 2 x (8.39+8.39) MB
        u16*   xTi  = xTr + (size_t)HWS * 64;
        u32*   vpk  = (u32*)(base + 202113024);            // 2 x 16,777,216 B
        u16*   wbf  = (u16*)(base + 235667456);
        float* rnsum = (float*)(base + 235741184);
        float* attn  = rnsum + 512;
        float* Pbuf  = attn + 16384;
        u16*   Abig  = (u16*)(Pbuf + 16384);

        const size_t XT_ST = 8388608;     // u16 per b (both planes)
        const size_t QS_ST = 12681216;    // u32 per b
        const size_t DW_ST = 16777216;    // u16 per b
        const size_t VP_ST = 4194304;     // u32 per b

        k_prep<<<66, 256, 0, stream>>>(qkv_wr, qkv_wi, wbf, rnsum, 512 + 16384);
        k_xt<<<dim3(1024, 1, 2), 256, 0, stream>>>(x, xTr, xTi, OSTR, XT_ST);
        // NPR = 516 row-pairs; grid = 8*6*ceil(516/8) = 3120
        k_qkv<<<3120, 256, 0, stream>>>(xTr, xTi, wbf, qs, XT_ST, QS_ST, 516);
        k_dw<<<dim3(12288, 1, 2), 256, 0, stream>>>(qs, dw_wr, dw_wi, dwp, vpk,
                                                    QS_ST, DW_ST, VP_ST);
        k_qk<<<dim3(64, 2, 2), 256, 0, stream>>>(dwp, rnsum, attn, 0, DW_ST);
        k_prob<<<dim3(2, 2), 64, 0, stream>>>(attn, rnsum, Pbuf, 0);
        k_M<<<dim3(16, 2), 256, 0, stream>>>(Pbuf, p_wr, p_wi, Abig, 0);
        k_out2<<<dim3(1024, 1, 2), 256, 0, stream>>>(Abig, vpk, out, 0, VP_ST, OSTR);
        return;
    }

    // shared-buffer layouts (round-14 / round-13 proven paths)
    u32*   qs   = (u32*)base;                               // 50,724,864 B
    u16*   dwp  = (u16*)(base + 50724864);                  // 33,554,432 B
    char*  xreg = base + 50724864 + 33554432;               // 16,777,216 B
    u16*   xTr  = (u16*)xreg;
    u16*   xTi  = xTr + (size_t)HWS * 64;
    u32*   vT   = (u32*)xreg;                               // fallback-13: vT aliases xT
    u32*   vpkW = (u32*)(base + 101056512);                 // f14 only
    size_t tail = f14 ? 117833728ull : 101056512ull;
    u16*   wbf  = (u16*)(base + tail);
    float* rnsum = (float*)(base + tail + 73728);
    float* attn  = rnsum + 512;
    float* Pbuf  = attn + 16384;
    u16*   Abig  = (u16*)(Pbuf + 16384);

    k_prep<<<66, 256, 0, stream>>>(qkv_wr, qkv_wi, wbf, rnsum, 512 + 16384);

    for (int b = 0; b < 2; ++b) {
        const float* xb = x + (size_t)b * OSTR;
        u32* vpack = f14 ? vpkW : (u32*)(out + (size_t)b * OSTR);
        k_xt<<<dim3(1024, 1, 1), 256, 0, stream>>>(xb, xTr, xTi, 0, 0);
        // NPR = 258; grid = 8*6*ceil(258/8) = 1584
        k_qkv<<<1584, 256, 0, stream>>>(xTr, xTi, wbf, qs, 0, 0, 258);
        k_dw<<<dim3(12288, 1, 1), 256, 0, stream>>>(qs, dw_wr, dw_wi, dwp, vpack, 0, 0, 0);
        k_qk<<<dim3(64, 2, 1), 256, 0, stream>>>(dwp, rnsum, attn, b, 0);
        k_prob<<<dim3(2, 1), 64, 0, stream>>>(attn, rnsum, Pbuf, b);
        k_M<<<dim3(16, 1), 256, 0, stream>>>(Pbuf, p_wr, p_wi, Abig, b);
        if (f14)
            k_out2<<<dim3(1024, 1, 1), 256, 0, stream>>>(Abig, vpkW,
                                                         out + (size_t)b * OSTR, b, 0, 0);
    }
    if (!f14) {
        for (int b = 0; b < 2; ++b) {
            u32* vpack = (u32*)(out + (size_t)b * OSTR);
            k_vt<<<1024, 256, 0, stream>>>(vpack, vT);
            k_out<<<1024, 256, 0, stream>>>(Abig + (size_t)b * 16384, (const u16*)vT,
                                            out + (size_t)b * OSTR);
        }
    }
}